// Round 5
// baseline (307.253 us; speedup 1.0000x reference)
//
#include <hip/hip_runtime.h>
#include <hip/hip_bf16.h>

typedef unsigned short u16;
typedef unsigned int   u32;
typedef _Float16 f16;
typedef __attribute__((ext_vector_type(4))) float f32x4;
typedef __attribute__((ext_vector_type(8))) short s16x8;
typedef __attribute__((ext_vector_type(8))) f16 f16x8;
typedef __attribute__((ext_vector_type(2))) __fp16 fp16x2;
typedef __attribute__((ext_vector_type(4))) u16 u16x4;
typedef __attribute__((ext_vector_type(2))) u32 u32x2;

#define DI __device__ __forceinline__

static constexpr int Bb = 2, Ss = 2048, Hh = 16, Dd = 64, Ee = 1024;
static constexpr int Mrows = Bb * Ss;              // 4096
static constexpr size_t NE = (size_t)Mrows * Ee;   // 4 M elems
static constexpr size_t WN = (size_t)Ee * Ee;      // 1 M elems
static constexpr float QSCALE = 0.125f * 1.44269504088896f;  // 1/8 * log2(e)

DI float bf2f(u16 h) { u32 u = ((u32)h) << 16; return __builtin_bit_cast(float, u); }
DI u16 f2bf(float f) {
    u32 u = __builtin_bit_cast(u32, f);
    u32 r = (u + 0x7FFFu + ((u >> 16) & 1u)) >> 16;
    return (u16)r;
}
DI u16 f2h(float f) { f16 h = (f16)f; return __builtin_bit_cast(u16, h); }
DI u32 pkrtz(float a, float b) {
    fp16x2 r = __builtin_amdgcn_cvt_pkrtz(a, b);
    return __builtin_bit_cast(u32, r);
}
DI float ex2(float x) { return __builtin_amdgcn_exp2f(x); }

#define MFMA_BF(a, b, c) __builtin_amdgcn_mfma_f32_16x16x32_bf16((a), (b), (c), 0, 0, 0)
#define MFMA_F16(a, b, c) __builtin_amdgcn_mfma_f32_16x16x32_f16( \
    __builtin_bit_cast(f16x8, (a)), __builtin_bit_cast(f16x8, (b)), (c), 0, 0, 0)

// async global->LDS, 16B per lane (LDS dest must be lane-linear)
DI void gld16(const u16* g, u16* l) {
    __builtin_amdgcn_global_load_lds((const __attribute__((address_space(1))) void*)g,
                                     (__attribute__((address_space(3))) void*)l, 16, 0, 0);
}

// ---------------- prep: q,k -> bf16 hi/lo; v -> fp16 ----------------
__global__ __launch_bounds__(256) void k_split3(
    const float* __restrict__ q, const float* __restrict__ k, const float* __restrict__ v,
    u16* __restrict__ qh, u16* __restrict__ ql,
    u16* __restrict__ kh, u16* __restrict__ kl, u16* __restrict__ vh) {
    int i = blockIdx.x * 256 + threadIdx.x;
    int y = blockIdx.y;
    if (y == 2) { vh[i] = f2h(v[i]); return; }
    const float* s = y ? k : q;
    u16* h = y ? kh : qh;
    u16* l = y ? kl : ql;
    float val = s[i];
    u16 hh = f2bf(val);
    h[i] = hh;
    l[i] = f2bf(val - bf2f(hh));
}

// ---------------- prep: weights -> B^T [N][K] via LDS-tiled transpose ----------------
__global__ __launch_bounds__(256) void k_wprep(
    const float* __restrict__ Wq, const float* __restrict__ Wk,
    const float* __restrict__ Wv, const float* __restrict__ Wo,
    u16* __restrict__ WqTh, u16* __restrict__ WqTl,
    u16* __restrict__ WkTh, u16* __restrict__ WkTl,
    u16* __restrict__ WvT, u16* __restrict__ WoT) {
    __shared__ float Ts[64 * 65];
    const int y = blockIdx.y;
    const int ti = blockIdx.x >> 4, tj = blockIdx.x & 15;   // n-tile, k-tile
    const float* W = (y == 0) ? Wq : (y == 1) ? Wk : (y == 2) ? Wv : Wo;
    const int t = threadIdx.x;
    const int col = t & 63, rb = (t >> 6) * 16;
#pragma unroll
    for (int rr = 0; rr < 16; rr++) {
        int row = rb + rr;   // k-local
        float v = (y < 3) ? W[(size_t)ti * 65536 + (size_t)(tj * 64 + row) * 64 + col]
                          : W[(size_t)(tj * 64 + row) * Ee + ti * 64 + col];
        Ts[row * 65 + col] = v;
    }
    __syncthreads();
#pragma unroll
    for (int rr = 0; rr < 16; rr++) {
        int orow = rb + rr;  // n-local
        int ocol = col;      // k-local (coalesced)
        float v = Ts[ocol * 65 + orow];
        size_t oidx = (size_t)(ti * 64 + orow) * Ee + tj * 64 + ocol;
        if (y == 0) {
            u16 hh = f2bf(v); WqTh[oidx] = hh; WqTl[oidx] = f2bf(v - bf2f(hh));
        } else if (y == 1) {
            u16 hh = f2bf(v); WkTh[oidx] = hh; WkTl[oidx] = f2bf(v - bf2f(hh));
        } else if (y == 2) {
            WvT[oidx] = f2h(v);
        } else {
            WoT[oidx] = f2h(v);
        }
    }
}

// ---------------- GEMM body, 128(M) x 128(N) tile (m97 structure) ----------------
// SPLIT=1: bf16 hi/lo 3-MFMA. F16=1: fp16 MFMA.
// OUTMODE: 0 = f32 row-major, 1 = fp16 transposed [N][M], 2 = bf16 hi/lo row-major.
template <int SPLIT, int F16, int OUTMODE>
DI void gemm_body(const u16* __restrict__ Ah, const u16* __restrict__ Al,
                  const u16* __restrict__ Bh, const u16* __restrict__ Bl,
                  const float* __restrict__ bias,
                  u16* __restrict__ C16h, u16* __restrict__ C16l, float* __restrict__ Cf,
                  float scale, u16* As0, u16* As1, u16* Bs0, u16* Bs1) {
    constexpr int M = Mrows, N = Ee, K = Ee;
    const int tid = threadIdx.x;
    const int wave = tid >> 6, lane = tid & 63;
    const int quad = lane >> 4, l16 = lane & 15;
    const int m0 = blockIdx.y * 128, n0 = blockIdx.x * 128;
    const int wm = (wave >> 1) * 64, wn = (wave & 1) * 64;

    f32x4 acc[4][4];
#pragma unroll
    for (int i = 0; i < 4; i++)
#pragma unroll
        for (int j = 0; j < 4; j++) acc[i][j] = (f32x4)0.0f;

    for (int kk = 0; kk < K; kk += 32) {
        __syncthreads();
        // A tile 128x32 + B tile 128x32, 16B lane-linear chunks
#pragma unroll
        for (int i = 0; i < 2; i++) {
            int c = tid + i * 256;
            int row = c >> 2, j = c & 3;
            size_t ga = (size_t)(m0 + row) * K + kk + j * 8;
            gld16(Ah + ga, As0 + c * 8);
            if constexpr (SPLIT) gld16(Al + ga, As1 + c * 8);
            size_t gb = (size_t)(n0 + row) * K + kk + j * 8;
            gld16(Bh + gb, Bs0 + c * 8);
            if constexpr (SPLIT) gld16(Bl + gb, Bs1 + c * 8);
        }
        __syncthreads();

        s16x8 bf[4][2];
#pragma unroll
        for (int nt = 0; nt < 4; nt++) {
            int r = wn + nt * 16 + l16;
            bf[nt][0] = *(const s16x8*)&Bs0[r * 32 + quad * 8];
            if constexpr (SPLIT) bf[nt][1] = *(const s16x8*)&Bs1[r * 32 + quad * 8];
        }
#pragma unroll
        for (int mt = 0; mt < 4; mt++) {
            int r = wm + mt * 16 + l16;
            s16x8 a0 = *(const s16x8*)&As0[r * 32 + quad * 8];
            s16x8 a1;
            if constexpr (SPLIT) a1 = *(const s16x8*)&As1[r * 32 + quad * 8];
#pragma unroll
            for (int nt = 0; nt < 4; nt++) {
                if constexpr (F16) {
                    acc[mt][nt] = MFMA_F16(a0, bf[nt][0], acc[mt][nt]);
                } else {
                    acc[mt][nt] = MFMA_BF(a0, bf[nt][0], acc[mt][nt]);
                    if constexpr (SPLIT) {
                        acc[mt][nt] = MFMA_BF(a0, bf[nt][1], acc[mt][nt]);
                        acc[mt][nt] = MFMA_BF(a1, bf[nt][0], acc[mt][nt]);
                    }
                }
            }
        }
    }

    // epilogue — C/D layout: col = lane&15, row = quad*4 + reg
#pragma unroll
    for (int mt = 0; mt < 4; mt++)
#pragma unroll
        for (int nt = 0; nt < 4; nt++) {
            int gn = n0 + wn + nt * 16 + l16;
            float bs = bias[gn];
            if constexpr (OUTMODE == 1) {
                int gm = m0 + wm + mt * 16 + quad * 4;
                u16x4 pk;
#pragma unroll
                for (int r = 0; r < 4; r++) pk[r] = f2h((acc[mt][nt][r] + bs) * scale);
                *(u16x4*)&C16h[(size_t)gn * M + gm] = pk;
            } else {
#pragma unroll
                for (int r = 0; r < 4; r++) {
                    int gm = m0 + wm + mt * 16 + quad * 4 + r;
                    float v = (acc[mt][nt][r] + bs) * scale;
                    if constexpr (OUTMODE == 0) {
                        Cf[(size_t)gm * N + gn] = v;
                    } else {
                        u16 hh = f2bf(v);
                        C16h[(size_t)gm * N + gn] = hh;
                        C16l[(size_t)gm * N + gn] = f2bf(v - bf2f(hh));
                    }
                }
            }
        }
}

// ---------------- fused Q/K/V projections (grid.z selects) ----------------
__global__ __launch_bounds__(256, 3) void k_qkv(
    const u16* __restrict__ qh, const u16* __restrict__ ql,
    const u16* __restrict__ kh, const u16* __restrict__ kl,
    const u16* __restrict__ vh,
    const u16* __restrict__ WqTh, const u16* __restrict__ WqTl,
    const u16* __restrict__ WkTh, const u16* __restrict__ WkTl,
    const u16* __restrict__ WvT,
    const float* __restrict__ bq, const float* __restrict__ bk, const float* __restrict__ bv,
    u16* __restrict__ Qh, u16* __restrict__ Ql2,
    u16* __restrict__ Kh, u16* __restrict__ Kl2, u16* __restrict__ Vt) {
    __shared__ u16 As[2][128 * 32];
    __shared__ u16 Bs[2][128 * 32];
    int z = blockIdx.z;
    if (z == 0)
        gemm_body<1, 0, 2>(qh, ql, WqTh, WqTl, bq, Qh, Ql2, nullptr, QSCALE,
                           As[0], As[1], Bs[0], Bs[1]);
    else if (z == 1)
        gemm_body<1, 0, 2>(kh, kl, WkTh, WkTl, bk, Kh, Kl2, nullptr, 1.0f,
                           As[0], As[1], Bs[0], Bs[1]);
    else
        gemm_body<0, 1, 1>(vh, nullptr, WvT, nullptr, bv, Vt, nullptr, nullptr, 1.0f,
                           As[0], As[1], Bs[0], Bs[1]);
}

// ---------------- output projection: ctx(fp16) @ WoT(fp16) + bo -> f32 ----------------
__global__ __launch_bounds__(256, 3) void k_out(
    const u16* __restrict__ ctx, const u16* __restrict__ WoT,
    const float* __restrict__ bo, float* __restrict__ out) {
    __shared__ u16 As[128 * 32];
    __shared__ u16 Bs[128 * 32];
    gemm_body<0, 1, 0>(ctx, nullptr, WoT, nullptr, bo, nullptr, nullptr, out, 1.0f,
                       As, nullptr, Bs, nullptr);
}

// ---------------- flash attention: 128q block, 32 q-cols/wave ----------------
// r10 model: 96us = ~9us MFMA + ~32us LDS + ~25us VALU + ~30us EXPOSED latency
// (staging loads serialized between barriers; serial QK->softmax->PV chain).
// This round: (1) T14 async-STAGE — next tile's 6 global loads issued at top of
// compute, ds_write after the post-PV barrier (latency hides under ~2000cyc of
// compute; m214 r277: +17%); (2) T5 setprio around MFMA clusters (m191: +4-7%);
// (3) loop-invariant LDS addresses hoisted (XOR swizzle computed once). Math
// bit-identical: bf16 hi/lo 3-MFMA scores (r5: fp16 scores absmax 432), exp2
// domain, QSCALE folded into Q. Grid x = bh -> XCD=bh%8 L2 reuse.
__global__ __launch_bounds__(256, 2) void k_attn(
    const u16* __restrict__ Qh, const u16* __restrict__ Ql,
    const u16* __restrict__ Kh, const u16* __restrict__ Kl,
    const u16* __restrict__ Vt, u16* __restrict__ ctx) {
    const int bh = blockIdx.x;
    const int b = bh >> 4, h = bh & 15;
    const int q0 = blockIdx.y * 128;
    const int rowBase = b * Ss + q0;
    const int hc = h * 64;

    __shared__ u16 Ks[2][64 * 64];     // [t][d] bf16 hi/lo, xor-swizzled (16 KB)
    __shared__ u16 Vs[64 * 64];        // [d][t] fp16, xor-swizzled (8 KB)
    __shared__ u16 Pw[4][32 * 72];     // per-wave [q 32][t 64], pad 72 (18.4 KB)

    const int tid = threadIdx.x;
    const int wave = tid >> 6, lane = tid & 63;
    const int quad = lane >> 4, l16 = lane & 15;

    // ---- staging coords (loop-invariant): 2 chunks of 16B per thread per array
    const int c0 = tid, c1 = tid + 256;
    const int srow0 = c0 >> 3, sgj0 = c0 & 7;
    const int srow1 = c1 >> 3, sgj1 = c1 & 7;
    const int soff0 = srow0 * 64 + (sgj0 ^ (srow0 & 7)) * 8;
    const int soff1 = srow1 * 64 + (sgj1 ^ (srow1 & 7)) * 8;

    s16x8 rkh0, rkh1, rkl0, rkl1, rv0, rv1;   // T14 in-flight staging regs
    auto loadT = [&](int t0) {
        const int kRowBase = b * Ss + t0;
        rkh0 = *(const s16x8*)(Kh + (size_t)(kRowBase + srow0) * Ee + hc + sgj0 * 8);
        rkl0 = *(const s16x8*)(Kl + (size_t)(kRowBase + srow0) * Ee + hc + sgj0 * 8);
        rv0  = *(const s16x8*)(Vt + (size_t)(hc + srow0) * Mrows + kRowBase + sgj0 * 8);
        rkh1 = *(const s16x8*)(Kh + (size_t)(kRowBase + srow1) * Ee + hc + sgj1 * 8);
        rkl1 = *(const s16x8*)(Kl + (size_t)(kRowBase + srow1) * Ee + hc + sgj1 * 8);
        rv1  = *(const s16x8*)(Vt + (size_t)(hc + srow1) * Mrows + kRowBase + sgj1 * 8);
    };
    auto storeT = [&]() {
        *(s16x8*)&Ks[0][soff0] = rkh0;
        *(s16x8*)&Ks[0][soff1] = rkh1;
        *(s16x8*)&Ks[1][soff0] = rkl0;
        *(s16x8*)&Ks[1][soff1] = rkl1;
        *(s16x8*)&Vs[soff0] = rv0;
        *(s16x8*)&Vs[soff1] = rv1;
    };

    // ---- hoisted loop-invariant LDS read/write addresses (constant offsets fold
    //      into ds_read/ds_write offset immediates)
    const int sw0 = ((0 * 4 + quad) ^ (l16 & 7)) * 8;
    const int sw1 = ((1 * 4 + quad) ^ (l16 & 7)) * 8;
    const u16* akb0 = &Ks[0][l16 * 64 + sw0];      // + mt*1024 (+4096 for lo plane)
    const u16* akb1 = &Ks[0][l16 * 64 + sw1];
    const u16* avb0 = &Vs[l16 * 64 + sw0];         // + dg*1024
    const u16* avb1 = &Vs[l16 * 64 + sw1];
    u16* pwb = &Pw[wave][l16 * 72 + quad * 4];     // + nt*1152 + mt*16
    const u16* pbb = &Pw[wave][l16 * 72 + quad * 8];  // + nt*1152 + kc*32

    // loop-invariant Q B-frags bq[nt][kc][hl] (lane n = q, k-contiguous 16B)
    s16x8 bq[2][2][2];
#pragma unroll
    for (int nt = 0; nt < 2; nt++) {
        int row = rowBase + wave * 32 + nt * 16 + l16;
#pragma unroll
        for (int kc = 0; kc < 2; kc++) {
            bq[nt][kc][0] = *(const s16x8*)(Qh + (size_t)row * Ee + hc + kc * 32 + quad * 8);
            bq[nt][kc][1] = *(const s16x8*)(Ql + (size_t)row * Ee + hc + kc * 32 + quad * 8);
        }
    }

    f32x4 o[2][4];   // [nt][dg]: O[d=dg*16+quad*4+r][q=wave*32+nt*16+l16]
#pragma unroll
    for (int nt = 0; nt < 2; nt++)
#pragma unroll
        for (int dg = 0; dg < 4; dg++) o[nt][dg] = (f32x4)0.0f;
    float m_[2] = {-1e30f, -1e30f};
    float l_[2] = {0.f, 0.f};

    // prologue: stage tile 0
    loadT(0);
    storeT();
    __syncthreads();

    for (int t0 = 0; t0 < Ss; t0 += 64) {
        const bool more = (t0 + 64) < Ss;
        if (more) loadT(t0 + 64);   // T14: issue early, lands during compute

        // S^T = K·Q^T (split); st[nt][mt]: t = mt*16 + quad*4 + r, q-col = nt, l16
        f32x4 st[2][4];
#pragma unroll
        for (int nt = 0; nt < 2; nt++)
#pragma unroll
            for (int mt = 0; mt < 4; mt++) st[nt][mt] = (f32x4)0.0f;
        __builtin_amdgcn_s_setprio(1);
#pragma unroll
        for (int mt = 0; mt < 4; mt++) {
            s16x8 akh0 = *(const s16x8*)(akb0 + mt * 1024);
            s16x8 akl0 = *(const s16x8*)(akb0 + mt * 1024 + 4096);
            s16x8 akh1 = *(const s16x8*)(akb1 + mt * 1024);
            s16x8 akl1 = *(const s16x8*)(akb1 + mt * 1024 + 4096);
#pragma unroll
            for (int nt = 0; nt < 2; nt++) {
                st[nt][mt] = MFMA_BF(akh0, bq[nt][0][0], st[nt][mt]);
                st[nt][mt] = MFMA_BF(akh0, bq[nt][0][1], st[nt][mt]);
                st[nt][mt] = MFMA_BF(akl0, bq[nt][0][0], st[nt][mt]);
                st[nt][mt] = MFMA_BF(akh1, bq[nt][1][0], st[nt][mt]);
                st[nt][mt] = MFMA_BF(akh1, bq[nt][1][1], st[nt][mt]);
                st[nt][mt] = MFMA_BF(akl1, bq[nt][1][0], st[nt][mt]);
            }
        }
        __builtin_amdgcn_s_setprio(0);

        // online softmax per q-column (2 per lane), exp2 domain, wave-local
#pragma unroll
        for (int nt = 0; nt < 2; nt++) {
            float t01 = fmaxf(fmaxf(st[nt][0][0], st[nt][0][1]), fmaxf(st[nt][0][2], st[nt][0][3]));
            float t23 = fmaxf(fmaxf(st[nt][1][0], st[nt][1][1]), fmaxf(st[nt][1][2], st[nt][1][3]));
            float t45 = fmaxf(fmaxf(st[nt][2][0], st[nt][2][1]), fmaxf(st[nt][2][2], st[nt][2][3]));
            float t67 = fmaxf(fmaxf(st[nt][3][0], st[nt][3][1]), fmaxf(st[nt][3][2], st[nt][3][3]));
            float tmax = fmaxf(fmaxf(t01, t23), fmaxf(t45, t67));
            tmax = fmaxf(tmax, __shfl_xor(tmax, 16));
            tmax = fmaxf(tmax, __shfl_xor(tmax, 32));
            float mnew = fmaxf(m_[nt], tmax);
            float al = ex2(m_[nt] - mnew);
            m_[nt] = mnew;
            float psum = 0.f;
#pragma unroll
            for (int mt = 0; mt < 4; mt++) {
                float p0 = ex2(st[nt][mt][0] - mnew);
                float p1 = ex2(st[nt][mt][1] - mnew);
                float p2 = ex2(st[nt][mt][2] - mnew);
                float p3 = ex2(st[nt][mt][3] - mnew);
                psum += (p0 + p1) + (p2 + p3);
                u32x2 pk;
                pk[0] = pkrtz(p0, p1);
                pk[1] = pkrtz(p2, p3);
                *(u32x2*)(pwb + nt * 1152 + mt * 16) = pk;
            }
            psum += __shfl_xor(psum, 16);
            psum += __shfl_xor(psum, 32);
            l_[nt] = l_[nt] * al + psum;
#pragma unroll
            for (int dg = 0; dg < 4; dg++) o[nt][dg] *= al;
        }

        // O^T += V^T P^T  (A = Vs[d][t], B = Pw[q][t], wave-private)
        __builtin_amdgcn_s_setprio(1);
#pragma unroll
        for (int kc = 0; kc < 2; kc++) {
            s16x8 bp[2];
#pragma unroll
            for (int nt = 0; nt < 2; nt++)
                bp[nt] = *(const s16x8*)(pbb + nt * 1152 + kc * 32);
            const u16* avb = kc ? avb1 : avb0;
#pragma unroll
            for (int dg = 0; dg < 4; dg++) {
                s16x8 av = *(const s16x8*)(avb + dg * 1024);
#pragma unroll
                for (int nt = 0; nt < 2; nt++) o[nt][dg] = MFMA_F16(av, bp[nt], o[nt][dg]);
            }
        }
        __builtin_amdgcn_s_setprio(0);

        if (more) {
            __syncthreads();   // all waves done reading Ks/Vs
            storeT();          // T14: write prefetched tile (vmcnt wait lands here)
            __syncthreads();   // new tile visible
        }
    }

    // epilogue: ctx[q][hc+d] fp16, d = dg*16 + quad*4 + r  -> 8B packed stores
#pragma unroll
    for (int nt = 0; nt < 2; nt++) {
        float inv = 1.0f / l_[nt];
        int gm = rowBase + wave * 32 + nt * 16 + l16;
#pragma unroll
        for (int dg = 0; dg < 4; dg++) {
            u32x2 pk;
            pk[0] = pkrtz(o[nt][dg][0] * inv, o[nt][dg][1] * inv);
            pk[1] = pkrtz(o[nt][dg][2] * inv, o[nt][dg][3] * inv);
            *(u32x2*)&ctx[(size_t)gm * Ee + hc + dg * 16 + quad * 4] = pk;
        }
    }
}

extern "C" void kernel_launch(void* const* d_in, const int* in_sizes, int n_in,
                              void* d_out, int out_size, void* d_ws, size_t ws_size,
                              hipStream_t stream) {
    const float* q   = (const float*)d_in[0];
    const float* kin = (const float*)d_in[1];
    const float* v   = (const float*)d_in[2];
    const float* Wq  = (const float*)d_in[3];
    const float* Wk  = (const float*)d_in[4];
    const float* Wv  = (const float*)d_in[5];
    const float* bq  = (const float*)d_in[6];
    const float* bk  = (const float*)d_in[7];
    const float* bv  = (const float*)d_in[8];
    const float* Wo  = (const float*)d_in[9];
    const float* bo  = (const float*)d_in[10];

    u16* ws = (u16*)d_ws;
    u16 *qh = ws,          *ql = ws + NE,     *kh = ws + 2 * NE, *kl = ws + 3 * NE;
    u16 *vh = ws + 4 * NE;
    u16 *Qh = ws + 5 * NE, *Ql = ws + 6 * NE, *Kh = ws + 7 * NE, *Kl = ws + 8 * NE;
    u16 *Vt = ws + 9 * NE, *ctx = ws + 10 * NE;
    u16 *WqTh = ws + 11 * NE;
    u16 *WqTl = WqTh + WN, *WkTh = WqTh + 2 * WN, *WkTl = WqTh + 3 * WN;
    u16 *WvT = WqTh + 4 * WN, *WoT = WqTh + 5 * WN;

    dim3 b256(256);
    k_split3<<<dim3(NE / 256, 3), b256, 0, stream>>>(q, kin, v, qh, ql, kh, kl, vh);
    k_wprep<<<dim3(256, 4), b256, 0, stream>>>(Wq, Wk, Wv, Wo,
                                               WqTh, WqTl, WkTh, WkTl, WvT, WoT);

    k_qkv<<<dim3(8, 32, 3), b256, 0, stream>>>(qh, ql, kh, kl, vh,
                                               WqTh, WqTl, WkTh, WkTl, WvT,
                                               bq, bk, bv, Qh, Ql, Kh, Kl, Vt);

    k_attn<<<dim3(Bb * Hh, Ss / 128), b256, 0, stream>>>(Qh, Ql, Kh, Kl, Vt, ctx);

    k_out<<<dim3(8, 32), b256, 0, stream>>>(ctx, WoT, bo, (float*)d_out);
}

// Round 6
// 304.836 us; speedup vs baseline: 1.0079x; 1.0079x over previous
//
#include <hip/hip_runtime.h>
#include <hip/hip_bf16.h>

typedef unsigned short u16;
typedef unsigned int   u32;
typedef _Float16 f16;
typedef __attribute__((ext_vector_type(4))) float f32x4;
typedef __attribute__((ext_vector_type(8))) short s16x8;
typedef __attribute__((ext_vector_type(8))) f16 f16x8;
typedef __attribute__((ext_vector_type(2))) __fp16 fp16x2;
typedef __attribute__((ext_vector_type(4))) u16 u16x4;
typedef __attribute__((ext_vector_type(2))) u32 u32x2;

#define DI __device__ __forceinline__

static constexpr int Bb = 2, Ss = 2048, Hh = 16, Dd = 64, Ee = 1024;
static constexpr int Mrows = Bb * Ss;              // 4096
static constexpr size_t NE = (size_t)Mrows * Ee;   // 4 M elems
static constexpr size_t WN = (size_t)Ee * Ee;      // 1 M elems
static constexpr float QSCALE = 0.125f * 1.44269504088896f;  // 1/8 * log2(e)

DI float bf2f(u16 h) { u32 u = ((u32)h) << 16; return __builtin_bit_cast(float, u); }
DI u16 f2bf(float f) {
    u32 u = __builtin_bit_cast(u32, f);
    u32 r = (u + 0x7FFFu + ((u >> 16) & 1u)) >> 16;
    return (u16)r;
}
DI u16 f2h(float f) { f16 h = (f16)f; return __builtin_bit_cast(u16, h); }
DI u32 pkrtz(float a, float b) {
    fp16x2 r = __builtin_amdgcn_cvt_pkrtz(a, b);
    return __builtin_bit_cast(u32, r);
}
DI float ex2(float x) { return __builtin_amdgcn_exp2f(x); }

#define MFMA_BF(a, b, c) __builtin_amdgcn_mfma_f32_16x16x32_bf16((a), (b), (c), 0, 0, 0)
#define MFMA_F16(a, b, c) __builtin_amdgcn_mfma_f32_16x16x32_f16( \
    __builtin_bit_cast(f16x8, (a)), __builtin_bit_cast(f16x8, (b)), (c), 0, 0, 0)

// async global->LDS, 16B per lane (LDS dest must be lane-linear)
DI void gld16(const u16* g, u16* l) {
    __builtin_amdgcn_global_load_lds((const __attribute__((address_space(1))) void*)g,
                                     (__attribute__((address_space(3))) void*)l, 16, 0, 0);
}

// ---------------- prep: q,k -> bf16 hi/lo; v -> fp16 ----------------
__global__ __launch_bounds__(256) void k_split3(
    const float* __restrict__ q, const float* __restrict__ k, const float* __restrict__ v,
    u16* __restrict__ qh, u16* __restrict__ ql,
    u16* __restrict__ kh, u16* __restrict__ kl, u16* __restrict__ vh) {
    int i = blockIdx.x * 256 + threadIdx.x;
    int y = blockIdx.y;
    if (y == 2) { vh[i] = f2h(v[i]); return; }
    const float* s = y ? k : q;
    u16* h = y ? kh : qh;
    u16* l = y ? kl : ql;
    float val = s[i];
    u16 hh = f2bf(val);
    h[i] = hh;
    l[i] = f2bf(val - bf2f(hh));
}

// ---------------- prep: weights -> B^T [N][K] via LDS-tiled transpose ----------------
__global__ __launch_bounds__(256) void k_wprep(
    const float* __restrict__ Wq, const float* __restrict__ Wk,
    const float* __restrict__ Wv, const float* __restrict__ Wo,
    u16* __restrict__ WqTh, u16* __restrict__ WqTl,
    u16* __restrict__ WkTh, u16* __restrict__ WkTl,
    u16* __restrict__ WvT, u16* __restrict__ WoT) {
    __shared__ float Ts[64 * 65];
    const int y = blockIdx.y;
    const int ti = blockIdx.x >> 4, tj = blockIdx.x & 15;   // n-tile, k-tile
    const float* W = (y == 0) ? Wq : (y == 1) ? Wk : (y == 2) ? Wv : Wo;
    const int t = threadIdx.x;
    const int col = t & 63, rb = (t >> 6) * 16;
#pragma unroll
    for (int rr = 0; rr < 16; rr++) {
        int row = rb + rr;   // k-local
        float v = (y < 3) ? W[(size_t)ti * 65536 + (size_t)(tj * 64 + row) * 64 + col]
                          : W[(size_t)(tj * 64 + row) * Ee + ti * 64 + col];
        Ts[row * 65 + col] = v;
    }
    __syncthreads();
#pragma unroll
    for (int rr = 0; rr < 16; rr++) {
        int orow = rb + rr;  // n-local
        int ocol = col;      // k-local (coalesced)
        float v = Ts[ocol * 65 + orow];
        size_t oidx = (size_t)(ti * 64 + orow) * Ee + tj * 64 + ocol;
        if (y == 0) {
            u16 hh = f2bf(v); WqTh[oidx] = hh; WqTl[oidx] = f2bf(v - bf2f(hh));
        } else if (y == 1) {
            u16 hh = f2bf(v); WkTh[oidx] = hh; WkTl[oidx] = f2bf(v - bf2f(hh));
        } else if (y == 2) {
            WvT[oidx] = f2h(v);
        } else {
            WoT[oidx] = f2h(v);
        }
    }
}

// ---------------- GEMM body, 128(M) x 128(N) tile (m97 structure) ----------------
// SPLIT=1: bf16 hi/lo 3-MFMA. F16=1: fp16 MFMA.
// OUTMODE: 0 = f32 row-major, 1 = fp16 transposed [N][M], 2 = bf16 hi/lo row-major.
template <int SPLIT, int F16, int OUTMODE>
DI void gemm_body(const u16* __restrict__ Ah, const u16* __restrict__ Al,
                  const u16* __restrict__ Bh, const u16* __restrict__ Bl,
                  const float* __restrict__ bias,
                  u16* __restrict__ C16h, u16* __restrict__ C16l, float* __restrict__ Cf,
                  float scale, u16* As0, u16* As1, u16* Bs0, u16* Bs1) {
    constexpr int M = Mrows, N = Ee, K = Ee;
    const int tid = threadIdx.x;
    const int wave = tid >> 6, lane = tid & 63;
    const int quad = lane >> 4, l16 = lane & 15;
    const int m0 = blockIdx.y * 128, n0 = blockIdx.x * 128;
    const int wm = (wave >> 1) * 64, wn = (wave & 1) * 64;

    f32x4 acc[4][4];
#pragma unroll
    for (int i = 0; i < 4; i++)
#pragma unroll
        for (int j = 0; j < 4; j++) acc[i][j] = (f32x4)0.0f;

    for (int kk = 0; kk < K; kk += 32) {
        __syncthreads();
        // A tile 128x32 + B tile 128x32, 16B lane-linear chunks
#pragma unroll
        for (int i = 0; i < 2; i++) {
            int c = tid + i * 256;
            int row = c >> 2, j = c & 3;
            size_t ga = (size_t)(m0 + row) * K + kk + j * 8;
            gld16(Ah + ga, As0 + c * 8);
            if constexpr (SPLIT) gld16(Al + ga, As1 + c * 8);
            size_t gb = (size_t)(n0 + row) * K + kk + j * 8;
            gld16(Bh + gb, Bs0 + c * 8);
            if constexpr (SPLIT) gld16(Bl + gb, Bs1 + c * 8);
        }
        __syncthreads();

        s16x8 bf[4][2];
#pragma unroll
        for (int nt = 0; nt < 4; nt++) {
            int r = wn + nt * 16 + l16;
            bf[nt][0] = *(const s16x8*)&Bs0[r * 32 + quad * 8];
            if constexpr (SPLIT) bf[nt][1] = *(const s16x8*)&Bs1[r * 32 + quad * 8];
        }
#pragma unroll
        for (int mt = 0; mt < 4; mt++) {
            int r = wm + mt * 16 + l16;
            s16x8 a0 = *(const s16x8*)&As0[r * 32 + quad * 8];
            s16x8 a1;
            if constexpr (SPLIT) a1 = *(const s16x8*)&As1[r * 32 + quad * 8];
#pragma unroll
            for (int nt = 0; nt < 4; nt++) {
                if constexpr (F16) {
                    acc[mt][nt] = MFMA_F16(a0, bf[nt][0], acc[mt][nt]);
                } else {
                    acc[mt][nt] = MFMA_BF(a0, bf[nt][0], acc[mt][nt]);
                    if constexpr (SPLIT) {
                        acc[mt][nt] = MFMA_BF(a0, bf[nt][1], acc[mt][nt]);
                        acc[mt][nt] = MFMA_BF(a1, bf[nt][0], acc[mt][nt]);
                    }
                }
            }
        }
    }

    // epilogue — C/D layout: col = lane&15, row = quad*4 + reg
#pragma unroll
    for (int mt = 0; mt < 4; mt++)
#pragma unroll
        for (int nt = 0; nt < 4; nt++) {
            int gn = n0 + wn + nt * 16 + l16;
            float bs = bias[gn];
            if constexpr (OUTMODE == 1) {
                int gm = m0 + wm + mt * 16 + quad * 4;
                u16x4 pk;
#pragma unroll
                for (int r = 0; r < 4; r++) pk[r] = f2h((acc[mt][nt][r] + bs) * scale);
                *(u16x4*)&C16h[(size_t)gn * M + gm] = pk;
            } else {
#pragma unroll
                for (int r = 0; r < 4; r++) {
                    int gm = m0 + wm + mt * 16 + quad * 4 + r;
                    float v = (acc[mt][nt][r] + bs) * scale;
                    if constexpr (OUTMODE == 0) {
                        Cf[(size_t)gm * N + gn] = v;
                    } else {
                        u16 hh = f2bf(v);
                        C16h[(size_t)gm * N + gn] = hh;
                        C16l[(size_t)gm * N + gn] = f2bf(v - bf2f(hh));
                    }
                }
            }
        }
}

// ---------------- fused Q/K/V projections (grid.z selects) ----------------
__global__ __launch_bounds__(256, 3) void k_qkv(
    const u16* __restrict__ qh, const u16* __restrict__ ql,
    const u16* __restrict__ kh, const u16* __restrict__ kl,
    const u16* __restrict__ vh,
    const u16* __restrict__ WqTh, const u16* __restrict__ WqTl,
    const u16* __restrict__ WkTh, const u16* __restrict__ WkTl,
    const u16* __restrict__ WvT,
    const float* __restrict__ bq, const float* __restrict__ bk, const float* __restrict__ bv,
    u16* __restrict__ Qh, u16* __restrict__ Ql2,
    u16* __restrict__ Kh, u16* __restrict__ Kl2, u16* __restrict__ Vt) {
    __shared__ u16 As[2][128 * 32];
    __shared__ u16 Bs[2][128 * 32];
    int z = blockIdx.z;
    if (z == 0)
        gemm_body<1, 0, 2>(qh, ql, WqTh, WqTl, bq, Qh, Ql2, nullptr, QSCALE,
                           As[0], As[1], Bs[0], Bs[1]);
    else if (z == 1)
        gemm_body<1, 0, 2>(kh, kl, WkTh, WkTl, bk, Kh, Kl2, nullptr, 1.0f,
                           As[0], As[1], Bs[0], Bs[1]);
    else
        gemm_body<0, 1, 1>(vh, nullptr, WvT, nullptr, bv, Vt, nullptr, nullptr, 1.0f,
                           As[0], As[1], Bs[0], Bs[1]);
}

// ---------------- output projection: ctx(fp16) @ WoT(fp16) + bo -> f32 ----------------
__global__ __launch_bounds__(256, 3) void k_out(
    const u16* __restrict__ ctx, const u16* __restrict__ WoT,
    const float* __restrict__ bo, float* __restrict__ out) {
    __shared__ u16 As[128 * 32];
    __shared__ u16 Bs[128 * 32];
    gemm_body<0, 1, 0>(ctx, nullptr, WoT, nullptr, bo, nullptr, nullptr, out, 1.0f,
                       As, nullptr, Bs, nullptr);
}

// ---------------- flash attention: 128q block, 32 q-cols/wave ----------------
// r12 post-mortem: T14 regs got sunk by the compiler (VGPR stayed 92); the
// barrier->storeT(vmcnt)->barrier window still serializes all waves per tile.
// This round: DOUBLE-BUFFERED K/V LDS -> ONE barrier per tile. Iter i computes
// buf[p], writes tile i+1 into buf[p^1] (legal: prior readers of buf[p^1]
// finished at the end-of-iter-(i-1) barrier), issues tile i+2 loads at iter
// end (a full compute phase ahead of the consuming storeT -> latency hidden,
// and loads can't sink across the __syncthreads). Each wave drains only its
// own vmcnt. LDS 66.4 KB, 2 blocks/CU (= grid limit). Math bit-identical:
// bf16 hi/lo 3-MFMA scores, exp2 domain, QSCALE folded into Q projection.
// V/P/ctx fp16. Grid x = bh -> XCD=bh%8 L2 reuse.
__global__ __launch_bounds__(256, 2) void k_attn(
    const u16* __restrict__ Qh, const u16* __restrict__ Ql,
    const u16* __restrict__ Kh, const u16* __restrict__ Kl,
    const u16* __restrict__ Vt, u16* __restrict__ ctx) {
    const int bh = blockIdx.x;
    const int b = bh >> 4, h = bh & 15;
    const int q0 = blockIdx.y * 128;
    const int rowBase = b * Ss + q0;
    const int hc = h * 64;

    __shared__ u16 Ks[2][2][64 * 64];  // [buf][plane][t*64+d] bf16, swizzled (32 KB)
    __shared__ u16 Vs[2][64 * 64];     // [buf][d*64+t] fp16, swizzled (16 KB)
    __shared__ u16 Pw[4][32 * 72];     // per-wave [q 32][t 64], pad 72 (18.4 KB)

    const int tid = threadIdx.x;
    const int wave = tid >> 6, lane = tid & 63;
    const int quad = lane >> 4, l16 = lane & 15;

    // ---- staging coords (loop-invariant): 2 chunks of 16B per thread per array
    const int c0 = tid, c1 = tid + 256;
    const int srow0 = c0 >> 3, sgj0 = c0 & 7;
    const int srow1 = c1 >> 3, sgj1 = c1 & 7;
    const int soff0 = srow0 * 64 + (sgj0 ^ (srow0 & 7)) * 8;
    const int soff1 = srow1 * 64 + (sgj1 ^ (srow1 & 7)) * 8;

    s16x8 rkh0, rkh1, rkl0, rkl1, rv0, rv1;   // in-flight staging regs
    auto loadT = [&](int t0) {
        const int kRowBase = b * Ss + t0;
        rkh0 = *(const s16x8*)(Kh + (size_t)(kRowBase + srow0) * Ee + hc + sgj0 * 8);
        rkl0 = *(const s16x8*)(Kl + (size_t)(kRowBase + srow0) * Ee + hc + sgj0 * 8);
        rv0  = *(const s16x8*)(Vt + (size_t)(hc + srow0) * Mrows + kRowBase + sgj0 * 8);
        rkh1 = *(const s16x8*)(Kh + (size_t)(kRowBase + srow1) * Ee + hc + sgj1 * 8);
        rkl1 = *(const s16x8*)(Kl + (size_t)(kRowBase + srow1) * Ee + hc + sgj1 * 8);
        rv1  = *(const s16x8*)(Vt + (size_t)(hc + srow1) * Mrows + kRowBase + sgj1 * 8);
    };
    auto storeT = [&](int bf) {
        u16* Kd = &Ks[bf][0][0];
        u16* Vd = &Vs[bf][0];
        *(s16x8*)&Kd[soff0] = rkh0;
        *(s16x8*)&Kd[soff1] = rkh1;
        *(s16x8*)&Kd[4096 + soff0] = rkl0;
        *(s16x8*)&Kd[4096 + soff1] = rkl1;
        *(s16x8*)&Vd[soff0] = rv0;
        *(s16x8*)&Vd[soff1] = rv1;
    };

    // ---- hoisted loop-invariant LDS lane offsets (u16 units)
    const int sw0 = ((0 * 4 + quad) ^ (l16 & 7)) * 8;
    const int sw1 = ((1 * 4 + quad) ^ (l16 & 7)) * 8;
    const int kro0 = l16 * 64 + sw0;   // + mt*1024 (+4096 lo plane) within K buffer
    const int kro1 = l16 * 64 + sw1;
    u16* pwb = &Pw[wave][l16 * 72 + quad * 4];        // + nt*1152 + mt*16
    const u16* pbb = &Pw[wave][l16 * 72 + quad * 8];  // + nt*1152 + kc*32

    // loop-invariant Q B-frags bq[nt][kc][hl] (lane n = q, k-contiguous 16B)
    s16x8 bq[2][2][2];
#pragma unroll
    for (int nt = 0; nt < 2; nt++) {
        int row = rowBase + wave * 32 + nt * 16 + l16;
#pragma unroll
        for (int kc = 0; kc < 2; kc++) {
            bq[nt][kc][0] = *(const s16x8*)(Qh + (size_t)row * Ee + hc + kc * 32 + quad * 8);
            bq[nt][kc][1] = *(const s16x8*)(Ql + (size_t)row * Ee + hc + kc * 32 + quad * 8);
        }
    }

    f32x4 o[2][4];   // [nt][dg]: O[d=dg*16+quad*4+r][q=wave*32+nt*16+l16]
#pragma unroll
    for (int nt = 0; nt < 2; nt++)
#pragma unroll
        for (int dg = 0; dg < 4; dg++) o[nt][dg] = (f32x4)0.0f;
    float m_[2] = {-1e30f, -1e30f};
    float l_[2] = {0.f, 0.f};

    // prologue: tile0 -> buf0; issue tile1 loads
    loadT(0);
    storeT(0);
    loadT(64);
    __syncthreads();

    for (int t0 = 0; t0 < Ss; t0 += 64) {
        const int p = (t0 >> 6) & 1;
        const u16* Kp = &Ks[p][0][0];
        const u16* Vp = &Vs[p][0];

        // S^T = K·Q^T (split); st[nt][mt]: t = mt*16 + quad*4 + r, q-col = nt, l16
        f32x4 st[2][4];
#pragma unroll
        for (int nt = 0; nt < 2; nt++)
#pragma unroll
            for (int mt = 0; mt < 4; mt++) st[nt][mt] = (f32x4)0.0f;
        __builtin_amdgcn_s_setprio(1);
#pragma unroll
        for (int mt = 0; mt < 4; mt++) {
            s16x8 akh0 = *(const s16x8*)(Kp + kro0 + mt * 1024);
            s16x8 akl0 = *(const s16x8*)(Kp + kro0 + mt * 1024 + 4096);
            s16x8 akh1 = *(const s16x8*)(Kp + kro1 + mt * 1024);
            s16x8 akl1 = *(const s16x8*)(Kp + kro1 + mt * 1024 + 4096);
#pragma unroll
            for (int nt = 0; nt < 2; nt++) {
                st[nt][mt] = MFMA_BF(akh0, bq[nt][0][0], st[nt][mt]);
                st[nt][mt] = MFMA_BF(akh0, bq[nt][0][1], st[nt][mt]);
                st[nt][mt] = MFMA_BF(akl0, bq[nt][0][0], st[nt][mt]);
                st[nt][mt] = MFMA_BF(akh1, bq[nt][1][0], st[nt][mt]);
                st[nt][mt] = MFMA_BF(akh1, bq[nt][1][1], st[nt][mt]);
                st[nt][mt] = MFMA_BF(akl1, bq[nt][1][0], st[nt][mt]);
            }
        }
        __builtin_amdgcn_s_setprio(0);

        // online softmax per q-column (2 per lane), exp2 domain, wave-local
#pragma unroll
        for (int nt = 0; nt < 2; nt++) {
            float t01 = fmaxf(fmaxf(st[nt][0][0], st[nt][0][1]), fmaxf(st[nt][0][2], st[nt][0][3]));
            float t23 = fmaxf(fmaxf(st[nt][1][0], st[nt][1][1]), fmaxf(st[nt][1][2], st[nt][1][3]));
            float t45 = fmaxf(fmaxf(st[nt][2][0], st[nt][2][1]), fmaxf(st[nt][2][2], st[nt][2][3]));
            float t67 = fmaxf(fmaxf(st[nt][3][0], st[nt][3][1]), fmaxf(st[nt][3][2], st[nt][3][3]));
            float tmax = fmaxf(fmaxf(t01, t23), fmaxf(t45, t67));
            tmax = fmaxf(tmax, __shfl_xor(tmax, 16));
            tmax = fmaxf(tmax, __shfl_xor(tmax, 32));
            float mnew = fmaxf(m_[nt], tmax);
            float al = ex2(m_[nt] - mnew);
            m_[nt] = mnew;
            float psum = 0.f;
#pragma unroll
            for (int mt = 0; mt < 4; mt++) {
                float p0 = ex2(st[nt][mt][0] - mnew);
                float p1 = ex2(st[nt][mt][1] - mnew);
                float p2 = ex2(st[nt][mt][2] - mnew);
                float p3 = ex2(st[nt][mt][3] - mnew);
                psum += (p0 + p1) + (p2 + p3);
                u32x2 pk;
                pk[0] = pkrtz(p0, p1);
                pk[1] = pkrtz(p2, p3);
                *(u32x2*)(pwb + nt * 1152 + mt * 16) = pk;
            }
            psum += __shfl_xor(psum, 16);
            psum += __shfl_xor(psum, 32);
            l_[nt] = l_[nt] * al + psum;
#pragma unroll
            for (int dg = 0; dg < 4; dg++) o[nt][dg] *= al;
        }

        // O^T += V^T P^T  (A = Vs[d][t], B = Pw[q][t], wave-private)
        __builtin_amdgcn_s_setprio(1);
#pragma unroll
        for (int kc = 0; kc < 2; kc++) {
            s16x8 bp[2];
#pragma unroll
            for (int nt = 0; nt < 2; nt++)
                bp[nt] = *(const s16x8*)(pbb + nt * 1152 + kc * 32);
            const int vro = kc ? kro1 : kro0;
#pragma unroll
            for (int dg = 0; dg < 4; dg++) {
                s16x8 av = *(const s16x8*)(Vp + vro + dg * 1024);
#pragma unroll
                for (int nt = 0; nt < 2; nt++) o[nt][dg] = MFMA_F16(av, bp[nt], o[nt][dg]);
            }
        }
        __builtin_amdgcn_s_setprio(0);

        // stage tile t0+64 (regs loaded last iter) into the other buffer;
        // issue loads for tile t0+128. One barrier per tile.
        if (t0 + 64 < Ss) {
            storeT(p ^ 1);
            if (t0 + 128 < Ss) loadT(t0 + 128);
        }
        __syncthreads();
    }

    // epilogue: ctx[q][hc+d] fp16, d = dg*16 + quad*4 + r  -> 8B packed stores
#pragma unroll
    for (int nt = 0; nt < 2; nt++) {
        float inv = 1.0f / l_[nt];
        int gm = rowBase + wave * 32 + nt * 16 + l16;
#pragma unroll
        for (int dg = 0; dg < 4; dg++) {
            u32x2 pk;
            pk[0] = pkrtz(o[nt][dg][0] * inv, o[nt][dg][1] * inv);
            pk[1] = pkrtz(o[nt][dg][2] * inv, o[nt][dg][3] * inv);
            *(u32x2*)&ctx[(size_t)gm * Ee + hc + dg * 16 + quad * 4] = pk;
        }
    }
}

extern "C" void kernel_launch(void* const* d_in, const int* in_sizes, int n_in,
                              void* d_out, int out_size, void* d_ws, size_t ws_size,
                              hipStream_t stream) {
    const float* q   = (const float*)d_in[0];
    const float* kin = (const float*)d_in[1];
    const float* v   = (const float*)d_in[2];
    const float* Wq  = (const float*)d_in[3];
    const float* Wk  = (const float*)d_in[4];
    const float* Wv  = (const float*)d_in[5];
    const float* bq  = (const float*)d_in[6];
    const float* bk  = (const float*)d_in[7];
    const float* bv  = (const float*)d_in[8];
    const float* Wo  = (const float*)d_in[9];
    const float* bo  = (const float*)d_in[10];

    u16* ws = (u16*)d_ws;
    u16 *qh = ws,          *ql = ws + NE,     *kh = ws + 2 * NE, *kl = ws + 3 * NE;
    u16 *vh = ws + 4 * NE;
    u16 *Qh = ws + 5 * NE, *Ql = ws + 6 * NE, *Kh = ws + 7 * NE, *Kl = ws + 8 * NE;
    u16 *Vt = ws + 9 * NE, *ctx = ws + 10 * NE;
    u16 *WqTh = ws + 11 * NE;
    u16 *WqTl = WqTh + WN, *WkTh = WqTh + 2 * WN, *WkTl = WqTh + 3 * WN;
    u16 *WvT = WqTh + 4 * WN, *WoT = WqTh + 5 * WN;

    dim3 b256(256);
    k_split3<<<dim3(NE / 256, 3), b256, 0, stream>>>(q, kin, v, qh, ql, kh, kl, vh);
    k_wprep<<<dim3(256, 4), b256, 0, stream>>>(Wq, Wk, Wv, Wo,
                                               WqTh, WqTl, WkTh, WkTl, WvT, WoT);

    k_qkv<<<dim3(8, 32, 3), b256, 0, stream>>>(qh, ql, kh, kl, vh,
                                               WqTh, WqTl, WkTh, WkTl, WvT,
                                               bq, bk, bv, Qh, Ql, Kh, Kl, Vt);

    k_attn<<<dim3(Bb * Hh, Ss / 128), b256, 0, stream>>>(Qh, Ql, Kh, Kl, Vt, ctx);

    k_out<<<dim3(8, 32), b256, 0, stream>>>(ctx, WoT, bo, (float*)d_out);
}

// Round 8
// 299.649 us; speedup vs baseline: 1.0254x; 1.0173x over previous
//
#include <hip/hip_runtime.h>
#include <hip/hip_bf16.h>

typedef unsigned short u16;
typedef unsigned int   u32;
typedef _Float16 f16;
typedef __attribute__((ext_vector_type(4))) float f32x4;
typedef __attribute__((ext_vector_type(8))) short s16x8;
typedef __attribute__((ext_vector_type(8))) f16 f16x8;
typedef __attribute__((ext_vector_type(2))) __fp16 fp16x2;
typedef __attribute__((ext_vector_type(4))) u16 u16x4;
typedef __attribute__((ext_vector_type(2))) u32 u32x2;

#define DI __device__ __forceinline__

static constexpr int Bb = 2, Ss = 2048, Hh = 16, Dd = 64, Ee = 1024;
static constexpr int Mrows = Bb * Ss;              // 4096
static constexpr size_t NE = (size_t)Mrows * Ee;   // 4 M elems
static constexpr size_t WN = (size_t)Ee * Ee;      // 1 M elems
static constexpr float QSCALE = 0.125f * 1.44269504088896f;  // 1/8 * log2(e)

DI float bf2f(u16 h) { u32 u = ((u32)h) << 16; return __builtin_bit_cast(float, u); }
DI u16 f2bf(float f) {
    u32 u = __builtin_bit_cast(u32, f);
    u32 r = (u + 0x7FFFu + ((u >> 16) & 1u)) >> 16;
    return (u16)r;
}
DI u16 f2h(float f) { f16 h = (f16)f; return __builtin_bit_cast(u16, h); }
DI u32 pkrtz(float a, float b) {
    fp16x2 r = __builtin_amdgcn_cvt_pkrtz(a, b);
    return __builtin_bit_cast(u32, r);
}
DI float ex2(float x) { return __builtin_amdgcn_exp2f(x); }

#define MFMA_BF(a, b, c) __builtin_amdgcn_mfma_f32_16x16x32_bf16((a), (b), (c), 0, 0, 0)
#define MFMA_F16(a, b, c) __builtin_amdgcn_mfma_f32_16x16x32_f16( \
    __builtin_bit_cast(f16x8, (a)), __builtin_bit_cast(f16x8, (b)), (c), 0, 0, 0)

// async global->LDS, 16B per lane (LDS dest is wave-uniform base + lane*16)
DI void gld16(const u16* g, u16* l) {
    __builtin_amdgcn_global_load_lds((const __attribute__((address_space(1))) void*)g,
                                     (__attribute__((address_space(3))) void*)l, 16, 0, 0);
}

// ---------------- prep: q,k -> bf16 hi/lo; v -> fp16 ----------------
__global__ __launch_bounds__(256) void k_split3(
    const float* __restrict__ q, const float* __restrict__ k, const float* __restrict__ v,
    u16* __restrict__ qh, u16* __restrict__ ql,
    u16* __restrict__ kh, u16* __restrict__ kl, u16* __restrict__ vh) {
    int i = blockIdx.x * 256 + threadIdx.x;
    int y = blockIdx.y;
    if (y == 2) { vh[i] = f2h(v[i]); return; }
    const float* s = y ? k : q;
    u16* h = y ? kh : qh;
    u16* l = y ? kl : ql;
    float val = s[i];
    u16 hh = f2bf(val);
    h[i] = hh;
    l[i] = f2bf(val - bf2f(hh));
}

// ---------------- prep: weights -> B^T [N][K] via LDS-tiled transpose ----------------
__global__ __launch_bounds__(256) void k_wprep(
    const float* __restrict__ Wq, const float* __restrict__ Wk,
    const float* __restrict__ Wv, const float* __restrict__ Wo,
    u16* __restrict__ WqTh, u16* __restrict__ WqTl,
    u16* __restrict__ WkTh, u16* __restrict__ WkTl,
    u16* __restrict__ WvT, u16* __restrict__ WoT) {
    __shared__ float Ts[64 * 65];
    const int y = blockIdx.y;
    const int ti = blockIdx.x >> 4, tj = blockIdx.x & 15;   // n-tile, k-tile
    const float* W = (y == 0) ? Wq : (y == 1) ? Wk : (y == 2) ? Wv : Wo;
    const int t = threadIdx.x;
    const int col = t & 63, rb = (t >> 6) * 16;
#pragma unroll
    for (int rr = 0; rr < 16; rr++) {
        int row = rb + rr;   // k-local
        float v = (y < 3) ? W[(size_t)ti * 65536 + (size_t)(tj * 64 + row) * 64 + col]
                          : W[(size_t)(tj * 64 + row) * Ee + ti * 64 + col];
        Ts[row * 65 + col] = v;
    }
    __syncthreads();
#pragma unroll
    for (int rr = 0; rr < 16; rr++) {
        int orow = rb + rr;  // n-local
        int ocol = col;      // k-local (coalesced)
        float v = Ts[ocol * 65 + orow];
        size_t oidx = (size_t)(ti * 64 + orow) * Ee + tj * 64 + ocol;
        if (y == 0) {
            u16 hh = f2bf(v); WqTh[oidx] = hh; WqTl[oidx] = f2bf(v - bf2f(hh));
        } else if (y == 1) {
            u16 hh = f2bf(v); WkTh[oidx] = hh; WkTl[oidx] = f2bf(v - bf2f(hh));
        } else if (y == 2) {
            WvT[oidx] = f2h(v);
        } else {
            WoT[oidx] = f2h(v);
        }
    }
}

// ---------------- GEMM body, 128(M) x 128(N) tile (m97 structure) ----------------
// SPLIT=1: bf16 hi/lo 3-MFMA. F16=1: fp16 MFMA.
// OUTMODE: 0 = f32 row-major, 1 = fp16 transposed [N][M], 2 = bf16 hi/lo row-major.
template <int SPLIT, int F16, int OUTMODE>
DI void gemm_body(const u16* __restrict__ Ah, const u16* __restrict__ Al,
                  const u16* __restrict__ Bh, const u16* __restrict__ Bl,
                  const float* __restrict__ bias,
                  u16* __restrict__ C16h, u16* __restrict__ C16l, float* __restrict__ Cf,
                  float scale, u16* As0, u16* As1, u16* Bs0, u16* Bs1) {
    constexpr int M = Mrows, N = Ee, K = Ee;
    const int tid = threadIdx.x;
    const int wave = tid >> 6, lane = tid & 63;
    const int quad = lane >> 4, l16 = lane & 15;
    const int m0 = blockIdx.y * 128, n0 = blockIdx.x * 128;
    const int wm = (wave >> 1) * 64, wn = (wave & 1) * 64;

    f32x4 acc[4][4];
#pragma unroll
    for (int i = 0; i < 4; i++)
#pragma unroll
        for (int j = 0; j < 4; j++) acc[i][j] = (f32x4)0.0f;

    for (int kk = 0; kk < K; kk += 32) {
        __syncthreads();
        // A tile 128x32 + B tile 128x32, 16B lane-linear chunks
#pragma unroll
        for (int i = 0; i < 2; i++) {
            int c = tid + i * 256;
            int row = c >> 2, j = c & 3;
            size_t ga = (size_t)(m0 + row) * K + kk + j * 8;
            gld16(Ah + ga, As0 + c * 8);
            if constexpr (SPLIT) gld16(Al + ga, As1 + c * 8);
            size_t gb = (size_t)(n0 + row) * K + kk + j * 8;
            gld16(Bh + gb, Bs0 + c * 8);
            if constexpr (SPLIT) gld16(Bl + gb, Bs1 + c * 8);
        }
        __syncthreads();

        s16x8 bf[4][2];
#pragma unroll
        for (int nt = 0; nt < 4; nt++) {
            int r = wn + nt * 16 + l16;
            bf[nt][0] = *(const s16x8*)&Bs0[r * 32 + quad * 8];
            if constexpr (SPLIT) bf[nt][1] = *(const s16x8*)&Bs1[r * 32 + quad * 8];
        }
#pragma unroll
        for (int mt = 0; mt < 4; mt++) {
            int r = wm + mt * 16 + l16;
            s16x8 a0 = *(const s16x8*)&As0[r * 32 + quad * 8];
            s16x8 a1;
            if constexpr (SPLIT) a1 = *(const s16x8*)&As1[r * 32 + quad * 8];
#pragma unroll
            for (int nt = 0; nt < 4; nt++) {
                if constexpr (F16) {
                    acc[mt][nt] = MFMA_F16(a0, bf[nt][0], acc[mt][nt]);
                } else {
                    acc[mt][nt] = MFMA_BF(a0, bf[nt][0], acc[mt][nt]);
                    if constexpr (SPLIT) {
                        acc[mt][nt] = MFMA_BF(a0, bf[nt][1], acc[mt][nt]);
                        acc[mt][nt] = MFMA_BF(a1, bf[nt][0], acc[mt][nt]);
                    }
                }
            }
        }
    }

    // epilogue — C/D layout: col = lane&15, row = quad*4 + reg
#pragma unroll
    for (int mt = 0; mt < 4; mt++)
#pragma unroll
        for (int nt = 0; nt < 4; nt++) {
            int gn = n0 + wn + nt * 16 + l16;
            float bs = bias[gn];
            if constexpr (OUTMODE == 1) {
                int gm = m0 + wm + mt * 16 + quad * 4;
                u16x4 pk;
#pragma unroll
                for (int r = 0; r < 4; r++) pk[r] = f2h((acc[mt][nt][r] + bs) * scale);
                *(u16x4*)&C16h[(size_t)gn * M + gm] = pk;
            } else {
#pragma unroll
                for (int r = 0; r < 4; r++) {
                    int gm = m0 + wm + mt * 16 + quad * 4 + r;
                    float v = (acc[mt][nt][r] + bs) * scale;
                    if constexpr (OUTMODE == 0) {
                        Cf[(size_t)gm * N + gn] = v;
                    } else {
                        u16 hh = f2bf(v);
                        C16h[(size_t)gm * N + gn] = hh;
                        C16l[(size_t)gm * N + gn] = f2bf(v - bf2f(hh));
                    }
                }
            }
        }
}

// ---------------- fused Q/K/V projections (grid.z selects) ----------------
__global__ __launch_bounds__(256, 3) void k_qkv(
    const u16* __restrict__ qh, const u16* __restrict__ ql,
    const u16* __restrict__ kh, const u16* __restrict__ kl,
    const u16* __restrict__ vh,
    const u16* __restrict__ WqTh, const u16* __restrict__ WqTl,
    const u16* __restrict__ WkTh, const u16* __restrict__ WkTl,
    const u16* __restrict__ WvT,
    const float* __restrict__ bq, const float* __restrict__ bk, const float* __restrict__ bv,
    u16* __restrict__ Qh, u16* __restrict__ Ql2,
    u16* __restrict__ Kh, u16* __restrict__ Kl2, u16* __restrict__ Vt) {
    __shared__ u16 As[2][128 * 32];
    __shared__ u16 Bs[2][128 * 32];
    int z = blockIdx.z;
    if (z == 0)
        gemm_body<1, 0, 2>(qh, ql, WqTh, WqTl, bq, Qh, Ql2, nullptr, QSCALE,
                           As[0], As[1], Bs[0], Bs[1]);
    else if (z == 1)
        gemm_body<1, 0, 2>(kh, kl, WkTh, WkTl, bk, Kh, Kl2, nullptr, 1.0f,
                           As[0], As[1], Bs[0], Bs[1]);
    else
        gemm_body<0, 1, 1>(vh, nullptr, WvT, nullptr, bv, Vt, nullptr, nullptr, 1.0f,
                           As[0], As[1], Bs[0], Bs[1]);
}

// ---------------- output projection: ctx(fp16) @ WoT(fp16) + bo -> f32 ----------------
__global__ __launch_bounds__(256, 3) void k_out(
    const u16* __restrict__ ctx, const u16* __restrict__ WoT,
    const float* __restrict__ bo, float* __restrict__ out) {
    __shared__ u16 As[128 * 32];
    __shared__ u16 Bs[128 * 32];
    gemm_body<0, 1, 0>(ctx, nullptr, WoT, nullptr, bo, nullptr, nullptr, out, 1.0f,
                       As, nullptr, Bs, nullptr);
}

// ---------------- flash attention: 128q block, 32 q-cols/wave ----------------
// r13 post-mortem: BOTH reg-staging pipelines (r11 T14, r12 dbuf) were defeated
// by the compiler sinking const-__restrict loads across __syncthreads (VGPR
// stayed 88; r12 dbuf even regressed 90->94 from extra ds_writes). Fix: stage
// K/V via global_load_lds (side-effecting, HW-async, cannot sink). Swizzle via
// rule #21: LINEAR LDS dest + INVERSE-swizzled global source (row is 128B
// contiguous, XOR is an involution) + swizzled read (unchanged). Double-buffer,
// stage issued at TOP of iter into the free buffer, one barrier/iter; the
// compiler's vmcnt(0)-before-barrier lands after the full compute phase ->
// latency hidden, 6 ds_write_b128/thread/iter removed. Math bit-identical:
// bf16 hi/lo 3-MFMA scores, exp2 domain, QSCALE folded into Q projection.
// V/P/ctx fp16. Grid x = bh -> XCD=bh%8 L2 reuse.
__global__ __launch_bounds__(256, 2) void k_attn(
    const u16* __restrict__ Qh, const u16* __restrict__ Ql,
    const u16* __restrict__ Kh, const u16* __restrict__ Kl,
    const u16* __restrict__ Vt, u16* __restrict__ ctx) {
    const int bh = blockIdx.x;
    const int b = bh >> 4, h = bh & 15;
    const int q0 = blockIdx.y * 128;
    const int rowBase = b * Ss + q0;
    const int hc = h * 64;

    __shared__ u16 Ks[2][2][64 * 64];  // [buf][plane][row*64 + chunk] (32 KB)
    __shared__ u16 Vs[2][64 * 64];     // [buf][row*64 + chunk] fp16 (16 KB)
    __shared__ u16 Pw[4][32 * 72];     // per-wave [q 32][t 64], pad 72 (18.4 KB)

    const int tid = threadIdx.x;
    const int wave = tid >> 6, lane = tid & 63;
    const int quad = lane >> 4, l16 = lane & 15;

    // ---- staging: 2 chunks of 16B per thread per array; LDS dest lane-linear
    //      (dest chunk j = c&7), global source chunk = j ^ (row&7) (involution)
    const int c0 = tid, c1 = tid + 256;
    const int srow0 = c0 >> 3, sj0 = (c0 & 7) ^ (srow0 & 7);
    const int srow1 = c1 >> 3, sj1 = (c1 & 7) ^ (srow1 & 7);

    auto stage = [&](int t0, int bf) {
        const size_t kb = (size_t)(b * Ss + t0) * Ee + hc;
        const size_t vb0 = (size_t)(hc + srow0) * Mrows + b * Ss + t0;
        const size_t vb1 = (size_t)(hc + srow1) * Mrows + b * Ss + t0;
        gld16(Kh + kb + (size_t)srow0 * Ee + sj0 * 8, &Ks[bf][0][c0 * 8]);
        gld16(Kh + kb + (size_t)srow1 * Ee + sj1 * 8, &Ks[bf][0][c1 * 8]);
        gld16(Kl + kb + (size_t)srow0 * Ee + sj0 * 8, &Ks[bf][1][c0 * 8]);
        gld16(Kl + kb + (size_t)srow1 * Ee + sj1 * 8, &Ks[bf][1][c1 * 8]);
        gld16(Vt + vb0 + sj0 * 8, &Vs[bf][c0 * 8]);
        gld16(Vt + vb1 + sj1 * 8, &Vs[bf][c1 * 8]);
    };

    // ---- hoisted loop-invariant LDS lane offsets (u16 units)
    const int sw0 = ((0 * 4 + quad) ^ (l16 & 7)) * 8;
    const int sw1 = ((1 * 4 + quad) ^ (l16 & 7)) * 8;
    const int kro0 = l16 * 64 + sw0;   // + mt*1024 (+4096 lo plane) within K buffer
    const int kro1 = l16 * 64 + sw1;
    u16* pwb = &Pw[wave][l16 * 72 + quad * 4];        // + nt*1152 + mt*16
    const u16* pbb = &Pw[wave][l16 * 72 + quad * 8];  // + nt*1152 + kc*32

    // loop-invariant Q B-frags bq[nt][kc][hl] (lane n = q, k-contiguous 16B)
    s16x8 bq[2][2][2];
#pragma unroll
    for (int nt = 0; nt < 2; nt++) {
        int row = rowBase + wave * 32 + nt * 16 + l16;
#pragma unroll
        for (int kc = 0; kc < 2; kc++) {
            bq[nt][kc][0] = *(const s16x8*)(Qh + (size_t)row * Ee + hc + kc * 32 + quad * 8);
            bq[nt][kc][1] = *(const s16x8*)(Ql + (size_t)row * Ee + hc + kc * 32 + quad * 8);
        }
    }

    f32x4 o[2][4];   // [nt][dg]: O[d=dg*16+quad*4+r][q=wave*32+nt*16+l16]
#pragma unroll
    for (int nt = 0; nt < 2; nt++)
#pragma unroll
        for (int dg = 0; dg < 4; dg++) o[nt][dg] = (f32x4)0.0f;
    float m_[2] = {-1e30f, -1e30f};
    float l_[2] = {0.f, 0.f};

    // prologue: tile0 -> buf0 (vmcnt(0) is implied before the barrier)
    stage(0, 0);
    __syncthreads();

    for (int t0 = 0; t0 < Ss; t0 += 64) {
        const int p = (t0 >> 6) & 1;
        // async-stage next tile into the free buffer (its readers finished at
        // the barrier ending the previous iter); drains at this iter's barrier
        if (t0 + 64 < Ss) stage(t0 + 64, p ^ 1);

        const u16* Kp = &Ks[p][0][0];
        const u16* Vp = &Vs[p][0];

        // S^T = K·Q^T (split); st[nt][mt]: t = mt*16 + quad*4 + r, q-col = nt, l16
        f32x4 st[2][4];
#pragma unroll
        for (int nt = 0; nt < 2; nt++)
#pragma unroll
            for (int mt = 0; mt < 4; mt++) st[nt][mt] = (f32x4)0.0f;
        __builtin_amdgcn_s_setprio(1);
#pragma unroll
        for (int mt = 0; mt < 4; mt++) {
            s16x8 akh0 = *(const s16x8*)(Kp + kro0 + mt * 1024);
            s16x8 akl0 = *(const s16x8*)(Kp + kro0 + mt * 1024 + 4096);
            s16x8 akh1 = *(const s16x8*)(Kp + kro1 + mt * 1024);
            s16x8 akl1 = *(const s16x8*)(Kp + kro1 + mt * 1024 + 4096);
#pragma unroll
            for (int nt = 0; nt < 2; nt++) {
                st[nt][mt] = MFMA_BF(akh0, bq[nt][0][0], st[nt][mt]);
                st[nt][mt] = MFMA_BF(akh0, bq[nt][0][1], st[nt][mt]);
                st[nt][mt] = MFMA_BF(akl0, bq[nt][0][0], st[nt][mt]);
                st[nt][mt] = MFMA_BF(akh1, bq[nt][1][0], st[nt][mt]);
                st[nt][mt] = MFMA_BF(akh1, bq[nt][1][1], st[nt][mt]);
                st[nt][mt] = MFMA_BF(akl1, bq[nt][1][0], st[nt][mt]);
            }
        }
        __builtin_amdgcn_s_setprio(0);

        // online softmax per q-column (2 per lane), exp2 domain, wave-local
#pragma unroll
        for (int nt = 0; nt < 2; nt++) {
            float t01 = fmaxf(fmaxf(st[nt][0][0], st[nt][0][1]), fmaxf(st[nt][0][2], st[nt][0][3]));
            float t23 = fmaxf(fmaxf(st[nt][1][0], st[nt][1][1]), fmaxf(st[nt][1][2], st[nt][1][3]));
            float t45 = fmaxf(fmaxf(st[nt][2][0], st[nt][2][1]), fmaxf(st[nt][2][2], st[nt][2][3]));
            float t67 = fmaxf(fmaxf(st[nt][3][0], st[nt][3][1]), fmaxf(st[nt][3][2], st[nt][3][3]));
            float tmax = fmaxf(fmaxf(t01, t23), fmaxf(t45, t67));
            tmax = fmaxf(tmax, __shfl_xor(tmax, 16));
            tmax = fmaxf(tmax, __shfl_xor(tmax, 32));
            float mnew = fmaxf(m_[nt], tmax);
            float al = ex2(m_[nt] - mnew);
            m_[nt] = mnew;
            float psum = 0.f;
#pragma unroll
            for (int mt = 0; mt < 4; mt++) {
                float p0 = ex2(st[nt][mt][0] - mnew);
                float p1 = ex2(st[nt][mt][1] - mnew);
                float p2 = ex2(st[nt][mt][2] - mnew);
                float p3 = ex2(st[nt][mt][3] - mnew);
                psum += (p0 + p1) + (p2 + p3);
                u32x2 pk;
                pk[0] = pkrtz(p0, p1);
                pk[1] = pkrtz(p2, p3);
                *(u32x2*)(pwb + nt * 1152 + mt * 16) = pk;
            }
            psum += __shfl_xor(psum, 16);
            psum += __shfl_xor(psum, 32);
            l_[nt] = l_[nt] * al + psum;
#pragma unroll
            for (int dg = 0; dg < 4; dg++) o[nt][dg] *= al;
        }

        // O^T += V^T P^T  (A = Vs[d][t], B = Pw[q][t], wave-private)
        __builtin_amdgcn_s_setprio(1);
#pragma unroll
        for (int kc = 0; kc < 2; kc++) {
            s16x8 bp[2];
#pragma unroll
            for (int nt = 0; nt < 2; nt++)
                bp[nt] = *(const s16x8*)(pbb + nt * 1152 + kc * 32);
            const int vro = kc ? kro1 : kro0;
#pragma unroll
            for (int dg = 0; dg < 4; dg++) {
                s16x8 av = *(const s16x8*)(Vp + vro + dg * 1024);
#pragma unroll
                for (int nt = 0; nt < 2; nt++) o[nt][dg] = MFMA_F16(av, bp[nt], o[nt][dg]);
            }
        }
        __builtin_amdgcn_s_setprio(0);

        __syncthreads();   // drains this iter's stage (vmcnt(0)) + flips buffer
    }

    // epilogue: ctx[q][hc+d] fp16, d = dg*16 + quad*4 + r  -> 8B packed stores
#pragma unroll
    for (int nt = 0; nt < 2; nt++) {
        float inv = 1.0f / l_[nt];
        int gm = rowBase + wave * 32 + nt * 16 + l16;
#pragma unroll
        for (int dg = 0; dg < 4; dg++) {
            u32x2 pk;
            pk[0] = pkrtz(o[nt][dg][0] * inv, o[nt][dg][1] * inv);
            pk[1] = pkrtz(o[nt][dg][2] * inv, o[nt][dg][3] * inv);
            *(u32x2*)&ctx[(size_t)gm * Ee + hc + dg * 16 + quad * 4] = pk;
        }
    }
}

extern "C" void kernel_launch(void* const* d_in, const int* in_sizes, int n_in,
                              void* d_out, int out_size, void* d_ws, size_t ws_size,
                              hipStream_t stream) {
    const float* q   = (const float*)d_in[0];
    const float* kin = (const float*)d_in[1];
    const float* v   = (const float*)d_in[2];
    const float* Wq  = (const float*)d_in[3];
    const float* Wk  = (const float*)d_in[4];
    const float* Wv  = (const float*)d_in[5];
    const float* bq  = (const float*)d_in[6];
    const float* bk  = (const float*)d_in[7];
    const float* bv  = (const float*)d_in[8];
    const float* Wo  = (const float*)d_in[9];
    const float* bo  = (const float*)d_in[10];

    u16* ws = (u16*)d_ws;
    u16 *qh = ws,          *ql = ws + NE,     *kh = ws + 2 * NE, *kl = ws + 3 * NE;
    u16 *vh = ws + 4 * NE;
    u16 *Qh = ws + 5 * NE, *Ql = ws + 6 * NE, *Kh = ws + 7 * NE, *Kl = ws + 8 * NE;
    u16 *Vt = ws + 9 * NE, *ctx = ws + 10 * NE;
    u16 *WqTh = ws + 11 * NE;
    u16 *WqTl = WqTh + WN, *WkTh = WqTh + 2 * WN, *WkTl = WqTh + 3 * WN;
    u16 *WvT = WqTh + 4 * WN, *WoT = WqTh + 5 * WN;

    dim3 b256(256);
    k_split3<<<dim3(NE / 256, 3), b256, 0, stream>>>(q, kin, v, qh, ql, kh, kl, vh);
    k_wprep<<<dim3(256, 4), b256, 0, stream>>>(Wq, Wk, Wv, Wo,
                                               WqTh, WqTl, WkTh, WkTl, WvT, WoT);

    k_qkv<<<dim3(8, 32, 3), b256, 0, stream>>>(qh, ql, kh, kl, vh,
                                               WqTh, WqTl, WkTh, WkTl, WvT,
                                               bq, bk, bv, Qh, Ql, Kh, Kl, Vt);

    k_attn<<<dim3(Bb * Hh, Ss / 128), b256, 0, stream>>>(Qh, Ql, Kh, Kl, Vt, ctx);

    k_out<<<dim3(8, 32), b256, 0, stream>>>(ctx, WoT, bo, (float*)d_out);
}

// Round 9
// 294.376 us; speedup vs baseline: 1.0437x; 1.0179x over previous
//
#include <hip/hip_runtime.h>
#include <hip/hip_bf16.h>

typedef unsigned short u16;
typedef unsigned int   u32;
typedef _Float16 f16;
typedef __attribute__((ext_vector_type(4))) float f32x4;
typedef __attribute__((ext_vector_type(16))) float f32x16;
typedef __attribute__((ext_vector_type(8))) short s16x8;
typedef __attribute__((ext_vector_type(8))) f16 f16x8;
typedef __attribute__((ext_vector_type(2))) __fp16 fp16x2;
typedef __attribute__((ext_vector_type(4))) u16 u16x4;
typedef __attribute__((ext_vector_type(2))) u32 u32x2;
typedef __attribute__((ext_vector_type(4))) u32 u32x4;

#define DI __device__ __forceinline__

static constexpr int Bb = 2, Ss = 2048, Hh = 16, Dd = 64, Ee = 1024;
static constexpr int Mrows = Bb * Ss;              // 4096
static constexpr size_t NE = (size_t)Mrows * Ee;   // 4 M elems
static constexpr size_t WN = (size_t)Ee * Ee;      // 1 M elems
static constexpr float QSCALE = 0.125f * 1.44269504088896f;  // 1/8 * log2(e)

DI float bf2f(u16 h) { u32 u = ((u32)h) << 16; return __builtin_bit_cast(float, u); }
DI u16 f2bf(float f) {
    u32 u = __builtin_bit_cast(u32, f);
    u32 r = (u + 0x7FFFu + ((u >> 16) & 1u)) >> 16;
    return (u16)r;
}
DI u16 f2h(float f) { f16 h = (f16)f; return __builtin_bit_cast(u16, h); }
DI u32 pkrtz(float a, float b) {
    fp16x2 r = __builtin_amdgcn_cvt_pkrtz(a, b);
    return __builtin_bit_cast(u32, r);
}
DI float ex2(float x) { return __builtin_amdgcn_exp2f(x); }

#define MFMA_BF(a, b, c) __builtin_amdgcn_mfma_f32_16x16x32_bf16((a), (b), (c), 0, 0, 0)
#define MFMA_F16(a, b, c) __builtin_amdgcn_mfma_f32_16x16x32_f16( \
    __builtin_bit_cast(f16x8, (a)), __builtin_bit_cast(f16x8, (b)), (c), 0, 0, 0)
#define MFMA32_BF(a, b, c) __builtin_amdgcn_mfma_f32_32x32x16_bf16((a), (b), (c), 0, 0, 0)
#define MFMA32_F16(a, b, c) __builtin_amdgcn_mfma_f32_32x32x16_f16( \
    __builtin_bit_cast(f16x8, (a)), __builtin_bit_cast(f16x8, (b)), (c), 0, 0, 0)

// async global->LDS, 16B per lane (LDS dest is wave-uniform base + lane*16)
DI void gld16(const u16* g, u16* l) {
    __builtin_amdgcn_global_load_lds((const __attribute__((address_space(1))) void*)g,
                                     (__attribute__((address_space(3))) void*)l, 16, 0, 0);
}

// ---------------- prep: q,k -> bf16 hi/lo; v -> fp16 ----------------
__global__ __launch_bounds__(256) void k_split3(
    const float* __restrict__ q, const float* __restrict__ k, const float* __restrict__ v,
    u16* __restrict__ qh, u16* __restrict__ ql,
    u16* __restrict__ kh, u16* __restrict__ kl, u16* __restrict__ vh) {
    int i = blockIdx.x * 256 + threadIdx.x;
    int y = blockIdx.y;
    if (y == 2) { vh[i] = f2h(v[i]); return; }
    const float* s = y ? k : q;
    u16* h = y ? kh : qh;
    u16* l = y ? kl : ql;
    float val = s[i];
    u16 hh = f2bf(val);
    h[i] = hh;
    l[i] = f2bf(val - bf2f(hh));
}

// ---------------- prep: weights -> B^T [N][K] via LDS-tiled transpose ----------------
__global__ __launch_bounds__(256) void k_wprep(
    const float* __restrict__ Wq, const float* __restrict__ Wk,
    const float* __restrict__ Wv, const float* __restrict__ Wo,
    u16* __restrict__ WqTh, u16* __restrict__ WqTl,
    u16* __restrict__ WkTh, u16* __restrict__ WkTl,
    u16* __restrict__ WvT, u16* __restrict__ WoT) {
    __shared__ float Ts[64 * 65];
    const int y = blockIdx.y;
    const int ti = blockIdx.x >> 4, tj = blockIdx.x & 15;   // n-tile, k-tile
    const float* W = (y == 0) ? Wq : (y == 1) ? Wk : (y == 2) ? Wv : Wo;
    const int t = threadIdx.x;
    const int col = t & 63, rb = (t >> 6) * 16;
#pragma unroll
    for (int rr = 0; rr < 16; rr++) {
        int row = rb + rr;   // k-local
        float v = (y < 3) ? W[(size_t)ti * 65536 + (size_t)(tj * 64 + row) * 64 + col]
                          : W[(size_t)(tj * 64 + row) * Ee + ti * 64 + col];
        Ts[row * 65 + col] = v;
    }
    __syncthreads();
#pragma unroll
    for (int rr = 0; rr < 16; rr++) {
        int orow = rb + rr;  // n-local
        int ocol = col;      // k-local (coalesced)
        float v = Ts[ocol * 65 + orow];
        size_t oidx = (size_t)(ti * 64 + orow) * Ee + tj * 64 + ocol;
        if (y == 0) {
            u16 hh = f2bf(v); WqTh[oidx] = hh; WqTl[oidx] = f2bf(v - bf2f(hh));
        } else if (y == 1) {
            u16 hh = f2bf(v); WkTh[oidx] = hh; WkTl[oidx] = f2bf(v - bf2f(hh));
        } else if (y == 2) {
            WvT[oidx] = f2h(v);
        } else {
            WoT[oidx] = f2h(v);
        }
    }
}

// ---------------- GEMM body, 128(M) x 128(N) tile (m97 structure) ----------------
// SPLIT=1: bf16 hi/lo 3-MFMA. F16=1: fp16 MFMA.
// OUTMODE: 0 = f32 row-major, 1 = fp16 transposed [N][M], 2 = bf16 hi/lo row-major.
template <int SPLIT, int F16, int OUTMODE>
DI void gemm_body(const u16* __restrict__ Ah, const u16* __restrict__ Al,
                  const u16* __restrict__ Bh, const u16* __restrict__ Bl,
                  const float* __restrict__ bias,
                  u16* __restrict__ C16h, u16* __restrict__ C16l, float* __restrict__ Cf,
                  float scale, u16* As0, u16* As1, u16* Bs0, u16* Bs1) {
    constexpr int M = Mrows, N = Ee, K = Ee;
    const int tid = threadIdx.x;
    const int wave = tid >> 6, lane = tid & 63;
    const int quad = lane >> 4, l16 = lane & 15;
    const int m0 = blockIdx.y * 128, n0 = blockIdx.x * 128;
    const int wm = (wave >> 1) * 64, wn = (wave & 1) * 64;

    f32x4 acc[4][4];
#pragma unroll
    for (int i = 0; i < 4; i++)
#pragma unroll
        for (int j = 0; j < 4; j++) acc[i][j] = (f32x4)0.0f;

    for (int kk = 0; kk < K; kk += 32) {
        __syncthreads();
        // A tile 128x32 + B tile 128x32, 16B lane-linear chunks
#pragma unroll
        for (int i = 0; i < 2; i++) {
            int c = tid + i * 256;
            int row = c >> 2, j = c & 3;
            size_t ga = (size_t)(m0 + row) * K + kk + j * 8;
            gld16(Ah + ga, As0 + c * 8);
            if constexpr (SPLIT) gld16(Al + ga, As1 + c * 8);
            size_t gb = (size_t)(n0 + row) * K + kk + j * 8;
            gld16(Bh + gb, Bs0 + c * 8);
            if constexpr (SPLIT) gld16(Bl + gb, Bs1 + c * 8);
        }
        __syncthreads();

        s16x8 bf[4][2];
#pragma unroll
        for (int nt = 0; nt < 4; nt++) {
            int r = wn + nt * 16 + l16;
            bf[nt][0] = *(const s16x8*)&Bs0[r * 32 + quad * 8];
            if constexpr (SPLIT) bf[nt][1] = *(const s16x8*)&Bs1[r * 32 + quad * 8];
        }
#pragma unroll
        for (int mt = 0; mt < 4; mt++) {
            int r = wm + mt * 16 + l16;
            s16x8 a0 = *(const s16x8*)&As0[r * 32 + quad * 8];
            s16x8 a1;
            if constexpr (SPLIT) a1 = *(const s16x8*)&As1[r * 32 + quad * 8];
#pragma unroll
            for (int nt = 0; nt < 4; nt++) {
                if constexpr (F16) {
                    acc[mt][nt] = MFMA_F16(a0, bf[nt][0], acc[mt][nt]);
                } else {
                    acc[mt][nt] = MFMA_BF(a0, bf[nt][0], acc[mt][nt]);
                    if constexpr (SPLIT) {
                        acc[mt][nt] = MFMA_BF(a0, bf[nt][1], acc[mt][nt]);
                        acc[mt][nt] = MFMA_BF(a1, bf[nt][0], acc[mt][nt]);
                    }
                }
            }
        }
    }

    // epilogue — C/D layout: col = lane&15, row = quad*4 + reg
#pragma unroll
    for (int mt = 0; mt < 4; mt++)
#pragma unroll
        for (int nt = 0; nt < 4; nt++) {
            int gn = n0 + wn + nt * 16 + l16;
            float bs = bias[gn];
            if constexpr (OUTMODE == 1) {
                int gm = m0 + wm + mt * 16 + quad * 4;
                u16x4 pk;
#pragma unroll
                for (int r = 0; r < 4; r++) pk[r] = f2h((acc[mt][nt][r] + bs) * scale);
                *(u16x4*)&C16h[(size_t)gn * M + gm] = pk;
            } else {
#pragma unroll
                for (int r = 0; r < 4; r++) {
                    int gm = m0 + wm + mt * 16 + quad * 4 + r;
                    float v = (acc[mt][nt][r] + bs) * scale;
                    if constexpr (OUTMODE == 0) {
                        Cf[(size_t)gm * N + gn] = v;
                    } else {
                        u16 hh = f2bf(v);
                        C16h[(size_t)gm * N + gn] = hh;
                        C16l[(size_t)gm * N + gn] = f2bf(v - bf2f(hh));
                    }
                }
            }
        }
}

// ---------------- fused Q/K/V projections (grid.z selects) ----------------
__global__ __launch_bounds__(256, 3) void k_qkv(
    const u16* __restrict__ qh, const u16* __restrict__ ql,
    const u16* __restrict__ kh, const u16* __restrict__ kl,
    const u16* __restrict__ vh,
    const u16* __restrict__ WqTh, const u16* __restrict__ WqTl,
    const u16* __restrict__ WkTh, const u16* __restrict__ WkTl,
    const u16* __restrict__ WvT,
    const float* __restrict__ bq, const float* __restrict__ bk, const float* __restrict__ bv,
    u16* __restrict__ Qh, u16* __restrict__ Ql2,
    u16* __restrict__ Kh, u16* __restrict__ Kl2, u16* __restrict__ Vt) {
    __shared__ u16 As[2][128 * 32];
    __shared__ u16 Bs[2][128 * 32];
    int z = blockIdx.z;
    if (z == 0)
        gemm_body<1, 0, 2>(qh, ql, WqTh, WqTl, bq, Qh, Ql2, nullptr, QSCALE,
                           As[0], As[1], Bs[0], Bs[1]);
    else if (z == 1)
        gemm_body<1, 0, 2>(kh, kl, WkTh, WkTl, bk, Kh, Kl2, nullptr, 1.0f,
                           As[0], As[1], Bs[0], Bs[1]);
    else
        gemm_body<0, 1, 1>(vh, nullptr, WvT, nullptr, bv, Vt, nullptr, nullptr, 1.0f,
                           As[0], As[1], Bs[0], Bs[1]);
}

// ---------------- output projection: ctx(fp16) @ WoT(fp16) + bo -> f32 ----------------
__global__ __launch_bounds__(256, 3) void k_out(
    const u16* __restrict__ ctx, const u16* __restrict__ WoT,
    const float* __restrict__ bo, float* __restrict__ out) {
    __shared__ u16 As[128 * 32];
    __shared__ u16 Bs[128 * 32];
    gemm_body<0, 1, 0>(ctx, nullptr, WoT, nullptr, bo, nullptr, nullptr, out, 1.0f,
                       As, nullptr, Bs, nullptr);
}

// ---------------- flash attention: 32x32 MFMA, in-register softmax (T12) ------------
// r15: staging variants (r11/r12/r13) all ~91us -> per-iter LDS+VALU work is the
// bound, dominated by the P LDS roundtrip. 32x32 restructure: S^T = K.Q^T with
// mfma_32x32x16 puts q = lane&31 (full row per lane); softmax lane-local + one
// shfl_xor(32); P redistributed to PV B-frags IN REGISTERS via 16 cvt_pkrtz + 8
// permlane32_swap (m214 recipe: pls(w(g0),w(g1)) gives each lane its own block's
// words). Pw LDS buffer deleted (-16 b64 writes, -4 b128 reads /wave-iter).
// O^T = V^T.P^T keeps col=q so m/l/rescale stay lane-local. K/V staging identical
// to r13 (gld_lds dbuf, inverse-swizzled source). Layouts: C/D 32x32 row =
// (reg&3)+8*(reg>>2)+4*(lane>>5), col = lane&31 [m74/m101]; A/B k = (lane>>5)*8+e.
__global__ __launch_bounds__(256, 2) void k_attn(
    const u16* __restrict__ Qh, const u16* __restrict__ Ql,
    const u16* __restrict__ Kh, const u16* __restrict__ Kl,
    const u16* __restrict__ Vt, u16* __restrict__ ctx) {
    const int bh = blockIdx.x;
    const int b = bh >> 4, h = bh & 15;
    const int q0 = blockIdx.y * 128;
    const int rowBase = b * Ss + q0;
    const int hc = h * 64;

    __shared__ u16 Ks[2][2][64 * 64];  // [buf][plane][row*64 + chunk] (32 KB)
    __shared__ u16 Vs[2][64 * 64];     // [buf][row*64 + chunk] fp16 (16 KB)

    const int tid = threadIdx.x;
    const int wave = tid >> 6, lane = tid & 63;
    const int l31 = lane & 31, hi = lane >> 5;
    const int swl = l31 & 7;

    // ---- staging: identical to r13 (linear LDS dest, inverse-swizzled source)
    const int c0 = tid, c1 = tid + 256;
    const int srow0 = c0 >> 3, sj0 = (c0 & 7) ^ (srow0 & 7);
    const int srow1 = c1 >> 3, sj1 = (c1 & 7) ^ (srow1 & 7);

    auto stage = [&](int t0, int bf) {
        const size_t kb = (size_t)(b * Ss + t0) * Ee + hc;
        const size_t vb0 = (size_t)(hc + srow0) * Mrows + b * Ss + t0;
        const size_t vb1 = (size_t)(hc + srow1) * Mrows + b * Ss + t0;
        gld16(Kh + kb + (size_t)srow0 * Ee + sj0 * 8, &Ks[bf][0][c0 * 8]);
        gld16(Kh + kb + (size_t)srow1 * Ee + sj1 * 8, &Ks[bf][0][c1 * 8]);
        gld16(Kl + kb + (size_t)srow0 * Ee + sj0 * 8, &Ks[bf][1][c0 * 8]);
        gld16(Kl + kb + (size_t)srow1 * Ee + sj1 * 8, &Ks[bf][1][c1 * 8]);
        gld16(Vt + vb0 + sj0 * 8, &Vs[bf][c0 * 8]);
        gld16(Vt + vb1 + sj1 * 8, &Vs[bf][c1 * 8]);
    };

    // loop-invariant Q B-frags: col q = l31, k = d = ks*16 + hi*8 + e
    s16x8 bqh[4], bql[4];
    {
        const size_t qoff = (size_t)(rowBase + wave * 32 + l31) * Ee + hc + hi * 8;
#pragma unroll
        for (int ks = 0; ks < 4; ks++) {
            bqh[ks] = *(const s16x8*)(Qh + qoff + ks * 16);
            bql[ks] = *(const s16x8*)(Ql + qoff + ks * 16);
        }
    }

    f32x16 o[2];   // [dt]: O^T row d = (r&3)+8*(r>>2)+4*hi+32*dt, col q = l31
    o[0] = (f32x16)0.0f;
    o[1] = (f32x16)0.0f;
    float m_ = -1e30f, l_ = 0.f;

    stage(0, 0);
    __syncthreads();

    for (int t0 = 0; t0 < Ss; t0 += 64) {
        const int p = (t0 >> 6) & 1;
        if (t0 + 64 < Ss) stage(t0 + 64, p ^ 1);

        const u16* Kp = &Ks[p][0][0];
        const u16* Vp = &Vs[p][0];

        // S^T = K.Q^T (split): st[mt] row t = crow(r,hi)+32*mt, col q = l31
        f32x16 st[2];
        st[0] = (f32x16)0.0f;
        st[1] = (f32x16)0.0f;
        __builtin_amdgcn_s_setprio(1);
#pragma unroll
        for (int mt = 0; mt < 2; mt++) {
            const int rb = (mt * 32 + l31) * 64;
#pragma unroll
            for (int ks = 0; ks < 4; ks++) {
                const int sj = ((2 * ks + hi) ^ swl) * 8;
                s16x8 akh = *(const s16x8*)(Kp + rb + sj);
                s16x8 akl = *(const s16x8*)(Kp + rb + sj + 4096);
                st[mt] = MFMA32_BF(akh, bqh[ks], st[mt]);
                st[mt] = MFMA32_BF(akh, bql[ks], st[mt]);
                st[mt] = MFMA32_BF(akl, bqh[ks], st[mt]);
            }
        }
        __builtin_amdgcn_s_setprio(0);

        // online softmax: q = l31 (lane-local), partner rows live in lane^32
        float tmax = st[0][0];
#pragma unroll
        for (int mt = 0; mt < 2; mt++)
#pragma unroll
            for (int r = 0; r < 16; r++) tmax = fmaxf(tmax, st[mt][r]);
        tmax = fmaxf(tmax, __shfl_xor(tmax, 32));
        float mnew = fmaxf(m_, tmax);
        float al = ex2(m_ - mnew);
        m_ = mnew;
        float psum = 0.f;
#pragma unroll
        for (int mt = 0; mt < 2; mt++)
#pragma unroll
            for (int r = 0; r < 16; r++) {
                st[mt][r] = ex2(st[mt][r] - mnew);
                psum += st[mt][r];
            }
        psum += __shfl_xor(psum, 32);
        l_ = l_ * al + psum;
        o[0] *= al;
        o[1] *= al;

        // P -> PV B-frags in registers: per kt, blocks g0=2kt (hi=0), g1=2kt+1
        // (hi=1). pls(a,b): a'={a_lo,b_lo}, b'={a_hi,b_hi} -> each lane collects
        // its own block's 8 t-values as {rA0, rB0, rA1, rB1}.
        s16x8 pa[4];
#pragma unroll
        for (int kt = 0; kt < 4; kt++) {
            const int G0 = 2 * kt, G1 = 2 * kt + 1;
            const int m0_ = G0 >> 2, r0_ = (G0 & 3) * 4;
            const int m1_ = G1 >> 2, r1_ = (G1 & 3) * 4;
            u32 wA0 = pkrtz(st[m0_][r0_ + 0], st[m0_][r0_ + 1]);
            u32 wB0 = pkrtz(st[m0_][r0_ + 2], st[m0_][r0_ + 3]);
            u32 wA1 = pkrtz(st[m1_][r1_ + 0], st[m1_][r1_ + 1]);
            u32 wB1 = pkrtz(st[m1_][r1_ + 2], st[m1_][r1_ + 3]);
            u32x2 rA = __builtin_amdgcn_permlane32_swap(wA0, wA1, false, false);
            u32x2 rB = __builtin_amdgcn_permlane32_swap(wB0, wB1, false, false);
            u32x4 w;
            w[0] = rA[0]; w[1] = rB[0]; w[2] = rA[1]; w[3] = rB[1];
            pa[kt] = __builtin_bit_cast(s16x8, w);
        }

        // O^T += V^T . P^T : A = V^T (row d, k t), B = pa (col q, k t)
        __builtin_amdgcn_s_setprio(1);
#pragma unroll
        for (int dt = 0; dt < 2; dt++) {
            const int rbv = (dt * 32 + l31) * 64;
#pragma unroll
            for (int kt = 0; kt < 4; kt++) {
                const int sj = ((2 * kt + hi) ^ swl) * 8;
                s16x8 av = *(const s16x8*)(Vp + rbv + sj);
                o[dt] = MFMA32_F16(av, pa[kt], o[dt]);
            }
        }
        __builtin_amdgcn_s_setprio(0);

        __syncthreads();   // drains this iter's stage (vmcnt(0)) + flips buffer
    }

    // epilogue: ctx[q][hc+d] fp16, d = j + 8g + 4hi + 32dt -> 8B packed stores
    float inv = 1.0f / l_;
    const size_t obase = (size_t)(rowBase + wave * 32 + l31) * Ee + hc + hi * 4;
#pragma unroll
    for (int dt = 0; dt < 2; dt++)
#pragma unroll
        for (int g = 0; g < 4; g++) {
            u32x2 pk;
            pk[0] = pkrtz(o[dt][g * 4 + 0] * inv, o[dt][g * 4 + 1] * inv);
            pk[1] = pkrtz(o[dt][g * 4 + 2] * inv, o[dt][g * 4 + 3] * inv);
            *(u32x2*)&ctx[obase + dt * 32 + g * 8] = pk;
        }
}

extern "C" void kernel_launch(void* const* d_in, const int* in_sizes, int n_in,
                              void* d_out, int out_size, void* d_ws, size_t ws_size,
                              hipStream_t stream) {
    const float* q   = (const float*)d_in[0];
    const float* kin = (const float*)d_in[1];
    const float* v   = (const float*)d_in[2];
    const float* Wq  = (const float*)d_in[3];
    const float* Wk  = (const float*)d_in[4];
    const float* Wv  = (const float*)d_in[5];
    const float* bq  = (const float*)d_in[6];
    const float* bk  = (const float*)d_in[7];
    const float* bv  = (const float*)d_in[8];
    const float* Wo  = (const float*)d_in[9];
    const float* bo  = (const float*)d_in[10];

    u16* ws = (u16*)d_ws;
    u16 *qh = ws,          *ql = ws + NE,     *kh = ws + 2 * NE, *kl = ws + 3 * NE;
    u16 *vh = ws + 4 * NE;
    u16 *Qh = ws + 5 * NE, *Ql = ws + 6 * NE, *Kh = ws + 7 * NE, *Kl = ws + 8 * NE;
    u16 *Vt = ws + 9 * NE, *ctx = ws + 10 * NE;
    u16 *WqTh = ws + 11 * NE;
    u16 *WqTl = WqTh + WN, *WkTh = WqTh + 2 * WN, *WkTl = WqTh + 3 * WN;
    u16 *WvT = WqTh + 4 * WN, *WoT = WqTh + 5 * WN;

    dim3 b256(256);
    k_split3<<<dim3(NE / 256, 3), b256, 0, stream>>>(q, kin, v, qh, ql, kh, kl, vh);
    k_wprep<<<dim3(256, 4), b256, 0, stream>>>(Wq, Wk, Wv, Wo,
                                               WqTh, WqTl, WkTh, WkTl, WvT, WoT);

    k_qkv<<<dim3(8, 32, 3), b256, 0, stream>>>(qh, ql, kh, kl, vh,
                                               WqTh, WqTl, WkTh, WkTl, WvT,
                                               bq, bk, bv, Qh, Ql, Kh, Kl, Vt);

    k_attn<<<dim3(Bb * Hh, Ss / 128), b256, 0, stream>>>(Qh, Ql, Kh, Kl, Vt, ctx);

    k_out<<<dim3(8, 32), b256, 0, stream>>>(ctx, WoT, bo, (float*)d_out);
}

// Round 10
// 291.760 us; speedup vs baseline: 1.0531x; 1.0090x over previous
//
#include <hip/hip_runtime.h>
#include <hip/hip_bf16.h>

typedef unsigned short u16;
typedef unsigned int   u32;
typedef _Float16 f16;
typedef __attribute__((ext_vector_type(4))) float f32x4;
typedef __attribute__((ext_vector_type(16))) float f32x16;
typedef __attribute__((ext_vector_type(8))) short s16x8;
typedef __attribute__((ext_vector_type(8))) f16 f16x8;
typedef __attribute__((ext_vector_type(2))) __fp16 fp16x2;
typedef __attribute__((ext_vector_type(4))) u16 u16x4;
typedef __attribute__((ext_vector_type(8))) u16 u16x8;
typedef __attribute__((ext_vector_type(2))) u32 u32x2;
typedef __attribute__((ext_vector_type(4))) u32 u32x4;

#define DI __device__ __forceinline__

static constexpr int Bb = 2, Ss = 2048, Hh = 16, Dd = 64, Ee = 1024;
static constexpr int Mrows = Bb * Ss;              // 4096
static constexpr size_t NE = (size_t)Mrows * Ee;   // 4 M elems
static constexpr size_t WN = (size_t)Ee * Ee;      // 1 M elems
static constexpr float QSCALE = 0.125f * 1.44269504088896f;  // 1/8 * log2(e)

DI float bf2f(u16 h) { u32 u = ((u32)h) << 16; return __builtin_bit_cast(float, u); }
DI u16 f2bf(float f) {
    u32 u = __builtin_bit_cast(u32, f);
    u32 r = (u + 0x7FFFu + ((u >> 16) & 1u)) >> 16;
    return (u16)r;
}
DI u16 f2h(float f) { f16 h = (f16)f; return __builtin_bit_cast(u16, h); }
DI u32 pkrtz(float a, float b) {
    fp16x2 r = __builtin_amdgcn_cvt_pkrtz(a, b);
    return __builtin_bit_cast(u32, r);
}
DI float ex2(float x) { return __builtin_amdgcn_exp2f(x); }

#define MFMA_BF(a, b, c) __builtin_amdgcn_mfma_f32_16x16x32_bf16((a), (b), (c), 0, 0, 0)
#define MFMA_F16(a, b, c) __builtin_amdgcn_mfma_f32_16x16x32_f16( \
    __builtin_bit_cast(f16x8, (a)), __builtin_bit_cast(f16x8, (b)), (c), 0, 0, 0)
#define MFMA32_BF(a, b, c) __builtin_amdgcn_mfma_f32_32x32x16_bf16((a), (b), (c), 0, 0, 0)
#define MFMA32_F16(a, b, c) __builtin_amdgcn_mfma_f32_32x32x16_f16( \
    __builtin_bit_cast(f16x8, (a)), __builtin_bit_cast(f16x8, (b)), (c), 0, 0, 0)

// async global->LDS, 16B per lane (LDS dest is wave-uniform base + lane*16)
DI void gld16(const u16* g, u16* l) {
    __builtin_amdgcn_global_load_lds((const __attribute__((address_space(1))) void*)g,
                                     (__attribute__((address_space(3))) void*)l, 16, 0, 0);
}

// ---------------- prep: q,k -> bf16 hi/lo; v -> fp16 (8 elems/thread) ----------------
__global__ __launch_bounds__(256) void k_split3(
    const float* __restrict__ q, const float* __restrict__ k, const float* __restrict__ v,
    u16* __restrict__ qh, u16* __restrict__ ql,
    u16* __restrict__ kh, u16* __restrict__ kl, u16* __restrict__ vh) {
    size_t i = ((size_t)blockIdx.x * 256 + threadIdx.x) * 8;
    int y = blockIdx.y;
    if (y == 2) {
        f32x4 a = *(const f32x4*)(v + i);
        f32x4 b2 = *(const f32x4*)(v + i + 4);
        u16x8 o_;
#pragma unroll
        for (int j = 0; j < 4; j++) { o_[j] = f2h(a[j]); o_[4 + j] = f2h(b2[j]); }
        *(u16x8*)(vh + i) = o_;
        return;
    }
    const float* s = y ? k : q;
    u16* h = y ? kh : qh;
    u16* l = y ? kl : ql;
    f32x4 a = *(const f32x4*)(s + i);
    f32x4 b2 = *(const f32x4*)(s + i + 4);
    u16x8 oh, ol;
#pragma unroll
    for (int j = 0; j < 4; j++) {
        u16 hh = f2bf(a[j]); oh[j] = hh; ol[j] = f2bf(a[j] - bf2f(hh));
        u16 h2 = f2bf(b2[j]); oh[4 + j] = h2; ol[4 + j] = f2bf(b2[j] - bf2f(h2));
    }
    *(u16x8*)(h + i) = oh;
    *(u16x8*)(l + i) = ol;
}

// ---------------- prep: weights -> B^T [N][K] via LDS-tiled transpose ----------------
__global__ __launch_bounds__(256) void k_wprep(
    const float* __restrict__ Wq, const float* __restrict__ Wk,
    const float* __restrict__ Wv, const float* __restrict__ Wo,
    u16* __restrict__ WqTh, u16* __restrict__ WqTl,
    u16* __restrict__ WkTh, u16* __restrict__ WkTl,
    u16* __restrict__ WvT, u16* __restrict__ WoT) {
    __shared__ float Ts[64 * 65];
    const int y = blockIdx.y;
    const int ti = blockIdx.x >> 4, tj = blockIdx.x & 15;   // n-tile, k-tile
    const float* W = (y == 0) ? Wq : (y == 1) ? Wk : (y == 2) ? Wv : Wo;
    const int t = threadIdx.x;
    const int col = t & 63, rb = (t >> 6) * 16;
#pragma unroll
    for (int rr = 0; rr < 16; rr++) {
        int row = rb + rr;   // k-local
        float v = (y < 3) ? W[(size_t)ti * 65536 + (size_t)(tj * 64 + row) * 64 + col]
                          : W[(size_t)(tj * 64 + row) * Ee + ti * 64 + col];
        Ts[row * 65 + col] = v;
    }
    __syncthreads();
#pragma unroll
    for (int rr = 0; rr < 16; rr++) {
        int orow = rb + rr;  // n-local
        int ocol = col;      // k-local (coalesced)
        float v = Ts[ocol * 65 + orow];
        size_t oidx = (size_t)(ti * 64 + orow) * Ee + tj * 64 + ocol;
        if (y == 0) {
            u16 hh = f2bf(v); WqTh[oidx] = hh; WqTl[oidx] = f2bf(v - bf2f(hh));
        } else if (y == 1) {
            u16 hh = f2bf(v); WkTh[oidx] = hh; WkTl[oidx] = f2bf(v - bf2f(hh));
        } else if (y == 2) {
            WvT[oidx] = f2h(v);
        } else {
            WoT[oidx] = f2h(v);
        }
    }
}

// ---------------- GEMM body, 128(M) x 128(N) tile (m97 structure) ----------------
// SPLIT=1: bf16 hi/lo 3-MFMA. F16=1: fp16 MFMA.
// OUTMODE: 0 = f32 row-major, 1 = fp16 transposed [N][M], 2 = bf16 hi/lo row-major.
template <int SPLIT, int F16, int OUTMODE>
DI void gemm_body(const u16* __restrict__ Ah, const u16* __restrict__ Al,
                  const u16* __restrict__ Bh, const u16* __restrict__ Bl,
                  const float* __restrict__ bias,
                  u16* __restrict__ C16h, u16* __restrict__ C16l, float* __restrict__ Cf,
                  float scale, u16* As0, u16* As1, u16* Bs0, u16* Bs1) {
    constexpr int M = Mrows, N = Ee, K = Ee;
    const int tid = threadIdx.x;
    const int wave = tid >> 6, lane = tid & 63;
    const int quad = lane >> 4, l16 = lane & 15;
    const int m0 = blockIdx.y * 128, n0 = blockIdx.x * 128;
    const int wm = (wave >> 1) * 64, wn = (wave & 1) * 64;

    f32x4 acc[4][4];
#pragma unroll
    for (int i = 0; i < 4; i++)
#pragma unroll
        for (int j = 0; j < 4; j++) acc[i][j] = (f32x4)0.0f;

    for (int kk = 0; kk < K; kk += 32) {
        __syncthreads();
        // A tile 128x32 + B tile 128x32, 16B lane-linear chunks
#pragma unroll
        for (int i = 0; i < 2; i++) {
            int c = tid + i * 256;
            int row = c >> 2, j = c & 3;
            size_t ga = (size_t)(m0 + row) * K + kk + j * 8;
            gld16(Ah + ga, As0 + c * 8);
            if constexpr (SPLIT) gld16(Al + ga, As1 + c * 8);
            size_t gb = (size_t)(n0 + row) * K + kk + j * 8;
            gld16(Bh + gb, Bs0 + c * 8);
            if constexpr (SPLIT) gld16(Bl + gb, Bs1 + c * 8);
        }
        __syncthreads();

        s16x8 bf[4][2];
#pragma unroll
        for (int nt = 0; nt < 4; nt++) {
            int r = wn + nt * 16 + l16;
            bf[nt][0] = *(const s16x8*)&Bs0[r * 32 + quad * 8];
            if constexpr (SPLIT) bf[nt][1] = *(const s16x8*)&Bs1[r * 32 + quad * 8];
        }
#pragma unroll
        for (int mt = 0; mt < 4; mt++) {
            int r = wm + mt * 16 + l16;
            s16x8 a0 = *(const s16x8*)&As0[r * 32 + quad * 8];
            s16x8 a1;
            if constexpr (SPLIT) a1 = *(const s16x8*)&As1[r * 32 + quad * 8];
#pragma unroll
            for (int nt = 0; nt < 4; nt++) {
                if constexpr (F16) {
                    acc[mt][nt] = MFMA_F16(a0, bf[nt][0], acc[mt][nt]);
                } else {
                    acc[mt][nt] = MFMA_BF(a0, bf[nt][0], acc[mt][nt]);
                    if constexpr (SPLIT) {
                        acc[mt][nt] = MFMA_BF(a0, bf[nt][1], acc[mt][nt]);
                        acc[mt][nt] = MFMA_BF(a1, bf[nt][0], acc[mt][nt]);
                    }
                }
            }
        }
    }

    // epilogue — C/D layout: col = lane&15, row = quad*4 + reg
#pragma unroll
    for (int mt = 0; mt < 4; mt++)
#pragma unroll
        for (int nt = 0; nt < 4; nt++) {
            int gn = n0 + wn + nt * 16 + l16;
            float bs = bias[gn];
            if constexpr (OUTMODE == 1) {
                int gm = m0 + wm + mt * 16 + quad * 4;
                u16x4 pk;
#pragma unroll
                for (int r = 0; r < 4; r++) pk[r] = f2h((acc[mt][nt][r] + bs) * scale);
                *(u16x4*)&C16h[(size_t)gn * M + gm] = pk;
            } else {
#pragma unroll
                for (int r = 0; r < 4; r++) {
                    int gm = m0 + wm + mt * 16 + quad * 4 + r;
                    float v = (acc[mt][nt][r] + bs) * scale;
                    if constexpr (OUTMODE == 0) {
                        Cf[(size_t)gm * N + gn] = v;
                    } else {
                        u16 hh = f2bf(v);
                        C16h[(size_t)gm * N + gn] = hh;
                        C16l[(size_t)gm * N + gn] = f2bf(v - bf2f(hh));
                    }
                }
            }
        }
}

// ---------------- fused Q/K/V projections (grid.z selects) ----------------
__global__ __launch_bounds__(256, 3) void k_qkv(
    const u16* __restrict__ qh, const u16* __restrict__ ql,
    const u16* __restrict__ kh, const u16* __restrict__ kl,
    const u16* __restrict__ vh,
    const u16* __restrict__ WqTh, const u16* __restrict__ WqTl,
    const u16* __restrict__ WkTh, const u16* __restrict__ WkTl,
    const u16* __restrict__ WvT,
    const float* __restrict__ bq, const float* __restrict__ bk, const float* __restrict__ bv,
    u16* __restrict__ Qh, u16* __restrict__ Ql2,
    u16* __restrict__ Kh, u16* __restrict__ Kl2, u16* __restrict__ Vt) {
    __shared__ u16 As[2][128 * 32];
    __shared__ u16 Bs[2][128 * 32];
    int z = blockIdx.z;
    if (z == 0)
        gemm_body<1, 0, 2>(qh, ql, WqTh, WqTl, bq, Qh, Ql2, nullptr, QSCALE,
                           As[0], As[1], Bs[0], Bs[1]);
    else if (z == 1)
        gemm_body<1, 0, 2>(kh, kl, WkTh, WkTl, bk, Kh, Kl2, nullptr, 1.0f,
                           As[0], As[1], Bs[0], Bs[1]);
    else
        gemm_body<0, 1, 1>(vh, nullptr, WvT, nullptr, bv, Vt, nullptr, nullptr, 1.0f,
                           As[0], As[1], Bs[0], Bs[1]);
}

// ---------------- output projection: ctx(fp16) @ WoT(fp16) + bo -> f32 ----------------
__global__ __launch_bounds__(256, 3) void k_out(
    const u16* __restrict__ ctx, const u16* __restrict__ WoT,
    const float* __restrict__ bo, float* __restrict__ out) {
    __shared__ u16 As[128 * 32];
    __shared__ u16 Bs[128 * 32];
    gemm_body<0, 1, 0>(ctx, nullptr, WoT, nullptr, bo, nullptr, nullptr, out, 1.0f,
                       As, nullptr, Bs, nullptr);
}

// ---------------- flash attention: 32x32 MFMA, in-register softmax (T12) ------------
// r16: r15's 32x32+T12 port = 91.5->84.3us (VGPR 80, LDS 49KB). This round adds
// defer-max (T13, m214: +5%): skip max-update + o-rescale when
// __all(tmax - m_ <= 8) — exp2-domain headroom 2^8=256, exact algebra (P scaled
// by 2^(m_new-m_old) consistently in l_ and o). Wave-uniform branch. Bank
// conflicts doubled r14->r15 (3.1M->6.3M, 4-lane row-groups share swizzle chunk);
// static bank model unreliable twice -> not chasing swizzle this round.
__global__ __launch_bounds__(256, 2) void k_attn(
    const u16* __restrict__ Qh, const u16* __restrict__ Ql,
    const u16* __restrict__ Kh, const u16* __restrict__ Kl,
    const u16* __restrict__ Vt, u16* __restrict__ ctx) {
    const int bh = blockIdx.x;
    const int b = bh >> 4, h = bh & 15;
    const int q0 = blockIdx.y * 128;
    const int rowBase = b * Ss + q0;
    const int hc = h * 64;

    __shared__ u16 Ks[2][2][64 * 64];  // [buf][plane][row*64 + chunk] (32 KB)
    __shared__ u16 Vs[2][64 * 64];     // [buf][row*64 + chunk] fp16 (16 KB)

    const int tid = threadIdx.x;
    const int wave = tid >> 6, lane = tid & 63;
    const int l31 = lane & 31, hi = lane >> 5;
    const int swl = l31 & 7;

    // ---- staging: linear LDS dest, inverse-swizzled global source (rule #21)
    const int c0 = tid, c1 = tid + 256;
    const int srow0 = c0 >> 3, sj0 = (c0 & 7) ^ (srow0 & 7);
    const int srow1 = c1 >> 3, sj1 = (c1 & 7) ^ (srow1 & 7);

    auto stage = [&](int t0, int bf) {
        const size_t kb = (size_t)(b * Ss + t0) * Ee + hc;
        const size_t vb0 = (size_t)(hc + srow0) * Mrows + b * Ss + t0;
        const size_t vb1 = (size_t)(hc + srow1) * Mrows + b * Ss + t0;
        gld16(Kh + kb + (size_t)srow0 * Ee + sj0 * 8, &Ks[bf][0][c0 * 8]);
        gld16(Kh + kb + (size_t)srow1 * Ee + sj1 * 8, &Ks[bf][0][c1 * 8]);
        gld16(Kl + kb + (size_t)srow0 * Ee + sj0 * 8, &Ks[bf][1][c0 * 8]);
        gld16(Kl + kb + (size_t)srow1 * Ee + sj1 * 8, &Ks[bf][1][c1 * 8]);
        gld16(Vt + vb0 + sj0 * 8, &Vs[bf][c0 * 8]);
        gld16(Vt + vb1 + sj1 * 8, &Vs[bf][c1 * 8]);
    };

    // loop-invariant Q B-frags: col q = l31, k = d = ks*16 + hi*8 + e
    s16x8 bqh[4], bql[4];
    {
        const size_t qoff = (size_t)(rowBase + wave * 32 + l31) * Ee + hc + hi * 8;
#pragma unroll
        for (int ks = 0; ks < 4; ks++) {
            bqh[ks] = *(const s16x8*)(Qh + qoff + ks * 16);
            bql[ks] = *(const s16x8*)(Ql + qoff + ks * 16);
        }
    }

    f32x16 o[2];   // [dt]: O^T row d = (r&3)+8*(r>>2)+4*hi+32*dt, col q = l31
    o[0] = (f32x16)0.0f;
    o[1] = (f32x16)0.0f;
    float m_ = -1e30f, l_ = 0.f;

    stage(0, 0);
    __syncthreads();

    for (int t0 = 0; t0 < Ss; t0 += 64) {
        const int p = (t0 >> 6) & 1;
        if (t0 + 64 < Ss) stage(t0 + 64, p ^ 1);

        const u16* Kp = &Ks[p][0][0];
        const u16* Vp = &Vs[p][0];

        // S^T = K.Q^T (split): st[mt] row t = crow(r,hi)+32*mt, col q = l31
        f32x16 st[2];
        st[0] = (f32x16)0.0f;
        st[1] = (f32x16)0.0f;
        __builtin_amdgcn_s_setprio(1);
#pragma unroll
        for (int mt = 0; mt < 2; mt++) {
            const int rb = (mt * 32 + l31) * 64;
#pragma unroll
            for (int ks = 0; ks < 4; ks++) {
                const int sj = ((2 * ks + hi) ^ swl) * 8;
                s16x8 akh = *(const s16x8*)(Kp + rb + sj);
                s16x8 akl = *(const s16x8*)(Kp + rb + sj + 4096);
                st[mt] = MFMA32_BF(akh, bqh[ks], st[mt]);
                st[mt] = MFMA32_BF(akh, bql[ks], st[mt]);
                st[mt] = MFMA32_BF(akl, bqh[ks], st[mt]);
            }
        }
        __builtin_amdgcn_s_setprio(0);

        // online softmax: q = l31 (lane-local), partner rows in lane^32.
        // T13 defer-max: keep old m_ while tmax <= m_ + 8 (exp2 domain).
        float tmax = st[0][0];
#pragma unroll
        for (int mt = 0; mt < 2; mt++)
#pragma unroll
            for (int r = 0; r < 16; r++) tmax = fmaxf(tmax, st[mt][r]);
        tmax = fmaxf(tmax, __shfl_xor(tmax, 32));
        if (!__all(tmax - m_ <= 8.0f)) {
            float mnew = fmaxf(m_, tmax);
            float al = ex2(m_ - mnew);
            m_ = mnew;
            l_ *= al;
            o[0] *= al;
            o[1] *= al;
        }
        float psum = 0.f;
#pragma unroll
        for (int mt = 0; mt < 2; mt++)
#pragma unroll
            for (int r = 0; r < 16; r++) {
                st[mt][r] = ex2(st[mt][r] - m_);
                psum += st[mt][r];
            }
        psum += __shfl_xor(psum, 32);
        l_ += psum;

        // P -> PV B-frags in registers: 16 cvt_pkrtz + 8 permlane32_swap
        s16x8 pa[4];
#pragma unroll
        for (int kt = 0; kt < 4; kt++) {
            const int G0 = 2 * kt, G1 = 2 * kt + 1;
            const int m0_ = G0 >> 2, r0_ = (G0 & 3) * 4;
            const int m1_ = G1 >> 2, r1_ = (G1 & 3) * 4;
            u32 wA0 = pkrtz(st[m0_][r0_ + 0], st[m0_][r0_ + 1]);
            u32 wB0 = pkrtz(st[m0_][r0_ + 2], st[m0_][r0_ + 3]);
            u32 wA1 = pkrtz(st[m1_][r1_ + 0], st[m1_][r1_ + 1]);
            u32 wB1 = pkrtz(st[m1_][r1_ + 2], st[m1_][r1_ + 3]);
            u32x2 rA = __builtin_amdgcn_permlane32_swap(wA0, wA1, false, false);
            u32x2 rB = __builtin_amdgcn_permlane32_swap(wB0, wB1, false, false);
            u32x4 w;
            w[0] = rA[0]; w[1] = rB[0]; w[2] = rA[1]; w[3] = rB[1];
            pa[kt] = __builtin_bit_cast(s16x8, w);
        }

        // O^T += V^T . P^T : A = V^T (row d, k t), B = pa (col q, k t)
        __builtin_amdgcn_s_setprio(1);
#pragma unroll
        for (int dt = 0; dt < 2; dt++) {
            const int rbv = (dt * 32 + l31) * 64;
#pragma unroll
            for (int kt = 0; kt < 4; kt++) {
                const int sj = ((2 * kt + hi) ^ swl) * 8;
                s16x8 av = *(const s16x8*)(Vp + rbv + sj);
                o[dt] = MFMA32_F16(av, pa[kt], o[dt]);
            }
        }
        __builtin_amdgcn_s_setprio(0);

        __syncthreads();   // drains this iter's stage (vmcnt(0)) + flips buffer
    }

    // epilogue: ctx[q][hc+d] fp16, d = j + 8g + 4hi + 32dt -> 8B packed stores
    float inv = 1.0f / l_;
    const size_t obase = (size_t)(rowBase + wave * 32 + l31) * Ee + hc + hi * 4;
#pragma unroll
    for (int dt = 0; dt < 2; dt++)
#pragma unroll
        for (int g = 0; g < 4; g++) {
            u32x2 pk;
            pk[0] = pkrtz(o[dt][g * 4 + 0] * inv, o[dt][g * 4 + 1] * inv);
            pk[1] = pkrtz(o[dt][g * 4 + 2] * inv, o[dt][g * 4 + 3] * inv);
            *(u32x2*)&ctx[obase + dt * 32 + g * 8] = pk;
        }
}

extern "C" void kernel_launch(void* const* d_in, const int* in_sizes, int n_in,
                              void* d_out, int out_size, void* d_ws, size_t ws_size,
                              hipStream_t stream) {
    const float* q   = (const float*)d_in[0];
    const float* kin = (const float*)d_in[1];
    const float* v   = (const float*)d_in[2];
    const float* Wq  = (const float*)d_in[3];
    const float* Wk  = (const float*)d_in[4];
    const float* Wv  = (const float*)d_in[5];
    const float* bq  = (const float*)d_in[6];
    const float* bk  = (const float*)d_in[7];
    const float* bv  = (const float*)d_in[8];
    const float* Wo  = (const float*)d_in[9];
    const float* bo  = (const float*)d_in[10];

    u16* ws = (u16*)d_ws;
    u16 *qh = ws,          *ql = ws + NE,     *kh = ws + 2 * NE, *kl = ws + 3 * NE;
    u16 *vh = ws + 4 * NE;
    u16 *Qh = ws + 5 * NE, *Ql = ws + 6 * NE, *Kh = ws + 7 * NE, *Kl = ws + 8 * NE;
    u16 *Vt = ws + 9 * NE, *ctx = ws + 10 * NE;
    u16 *WqTh = ws + 11 * NE;
    u16 *WqTl = WqTh + WN, *WkTh = WqTh + 2 * WN, *WkTl = WqTh + 3 * WN;
    u16 *WvT = WqTh + 4 * WN, *WoT = WqTh + 5 * WN;

    dim3 b256(256);
    k_split3<<<dim3(NE / 2048, 3), b256, 0, stream>>>(q, kin, v, qh, ql, kh, kl, vh);
    k_wprep<<<dim3(256, 4), b256, 0, stream>>>(Wq, Wk, Wv, Wo,
                                               WqTh, WqTl, WkTh, WkTl, WvT, WoT);

    k_qkv<<<dim3(8, 32, 3), b256, 0, stream>>>(qh, ql, kh, kl, vh,
                                               WqTh, WqTl, WkTh, WkTl, WvT,
                                               bq, bk, bv, Qh, Ql, Kh, Kl, Vt);

    k_attn<<<dim3(Bb * Hh, Ss / 128), b256, 0, stream>>>(Qh, Ql, Kh, Kl, Vt, ctx);

    k_out<<<dim3(8, 32), b256, 0, stream>>>(ctx, WoT, bo, (float*)d_out);
}

// Round 11
// 277.365 us; speedup vs baseline: 1.1078x; 1.0519x over previous
//
#include <hip/hip_runtime.h>
#include <hip/hip_bf16.h>

typedef unsigned short u16;
typedef unsigned int   u32;
typedef _Float16 f16;
typedef __attribute__((ext_vector_type(4))) float f32x4;
typedef __attribute__((ext_vector_type(16))) float f32x16;
typedef __attribute__((ext_vector_type(8))) short s16x8;
typedef __attribute__((ext_vector_type(8))) f16 f16x8;
typedef __attribute__((ext_vector_type(2))) __fp16 fp16x2;
typedef __attribute__((ext_vector_type(4))) u16 u16x4;
typedef __attribute__((ext_vector_type(8))) u16 u16x8;
typedef __attribute__((ext_vector_type(2))) u32 u32x2;
typedef __attribute__((ext_vector_type(4))) u32 u32x4;

#define DI __device__ __forceinline__

static constexpr int Bb = 2, Ss = 2048, Hh = 16, Dd = 64, Ee = 1024;
static constexpr int Mrows = Bb * Ss;              // 4096
static constexpr size_t NE = (size_t)Mrows * Ee;   // 4 M elems
static constexpr size_t WN = (size_t)Ee * Ee;      // 1 M elems
static constexpr float QSCALE = 0.125f * 1.44269504088896f;  // 1/8 * log2(e)

DI float bf2f(u16 h) { u32 u = ((u32)h) << 16; return __builtin_bit_cast(float, u); }
DI u16 f2bf(float f) {
    u32 u = __builtin_bit_cast(u32, f);
    u32 r = (u + 0x7FFFu + ((u >> 16) & 1u)) >> 16;
    return (u16)r;
}
DI u16 f2h(float f) { f16 h = (f16)f; return __builtin_bit_cast(u16, h); }
DI u32 pkrtz(float a, float b) {
    fp16x2 r = __builtin_amdgcn_cvt_pkrtz(a, b);
    return __builtin_bit_cast(u32, r);
}
DI float ex2(float x) { return __builtin_amdgcn_exp2f(x); }

#define MFMA_BF(a, b, c) __builtin_amdgcn_mfma_f32_16x16x32_bf16((a), (b), (c), 0, 0, 0)
#define MFMA_F16(a, b, c) __builtin_amdgcn_mfma_f32_16x16x32_f16( \
    __builtin_bit_cast(f16x8, (a)), __builtin_bit_cast(f16x8, (b)), (c), 0, 0, 0)
#define MFMA32_BF(a, b, c) __builtin_amdgcn_mfma_f32_32x32x16_bf16((a), (b), (c), 0, 0, 0)
#define MFMA32_F16(a, b, c) __builtin_amdgcn_mfma_f32_32x32x16_f16( \
    __builtin_bit_cast(f16x8, (a)), __builtin_bit_cast(f16x8, (b)), (c), 0, 0, 0)

// async global->LDS, 16B per lane (LDS dest is wave-uniform base + lane*16)
DI void gld16(const u16* g, u16* l) {
    __builtin_amdgcn_global_load_lds((const __attribute__((address_space(1))) void*)g,
                                     (__attribute__((address_space(3))) void*)l, 16, 0, 0);
}

// ---------------- prep: q,k -> bf16 hi/lo; v -> fp16 (8 elems/thread) ----------------
__global__ __launch_bounds__(256) void k_split3(
    const float* __restrict__ q, const float* __restrict__ k, const float* __restrict__ v,
    u16* __restrict__ qh, u16* __restrict__ ql,
    u16* __restrict__ kh, u16* __restrict__ kl, u16* __restrict__ vh) {
    size_t i = ((size_t)blockIdx.x * 256 + threadIdx.x) * 8;
    int y = blockIdx.y;
    if (y == 2) {
        f32x4 a = *(const f32x4*)(v + i);
        f32x4 b2 = *(const f32x4*)(v + i + 4);
        u16x8 o_;
#pragma unroll
        for (int j = 0; j < 4; j++) { o_[j] = f2h(a[j]); o_[4 + j] = f2h(b2[j]); }
        *(u16x8*)(vh + i) = o_;
        return;
    }
    const float* s = y ? k : q;
    u16* h = y ? kh : qh;
    u16* l = y ? kl : ql;
    f32x4 a = *(const f32x4*)(s + i);
    f32x4 b2 = *(const f32x4*)(s + i + 4);
    u16x8 oh, ol;
#pragma unroll
    for (int j = 0; j < 4; j++) {
        u16 hh = f2bf(a[j]); oh[j] = hh; ol[j] = f2bf(a[j] - bf2f(hh));
        u16 h2 = f2bf(b2[j]); oh[4 + j] = h2; ol[4 + j] = f2bf(b2[j] - bf2f(h2));
    }
    *(u16x8*)(h + i) = oh;
    *(u16x8*)(l + i) = ol;
}

// ---------------- prep: weights -> B^T [N][K] via LDS-tiled transpose ----------------
__global__ __launch_bounds__(256) void k_wprep(
    const float* __restrict__ Wq, const float* __restrict__ Wk,
    const float* __restrict__ Wv, const float* __restrict__ Wo,
    u16* __restrict__ WqTh, u16* __restrict__ WqTl,
    u16* __restrict__ WkTh, u16* __restrict__ WkTl,
    u16* __restrict__ WvT, u16* __restrict__ WoT) {
    __shared__ float Ts[64 * 65];
    const int y = blockIdx.y;
    const int ti = blockIdx.x >> 4, tj = blockIdx.x & 15;   // n-tile, k-tile
    const float* W = (y == 0) ? Wq : (y == 1) ? Wk : (y == 2) ? Wv : Wo;
    const int t = threadIdx.x;
    const int col = t & 63, rb = (t >> 6) * 16;
#pragma unroll
    for (int rr = 0; rr < 16; rr++) {
        int row = rb + rr;   // k-local
        float v = (y < 3) ? W[(size_t)ti * 65536 + (size_t)(tj * 64 + row) * 64 + col]
                          : W[(size_t)(tj * 64 + row) * Ee + ti * 64 + col];
        Ts[row * 65 + col] = v;
    }
    __syncthreads();
#pragma unroll
    for (int rr = 0; rr < 16; rr++) {
        int orow = rb + rr;  // n-local
        int ocol = col;      // k-local (coalesced)
        float v = Ts[ocol * 65 + orow];
        size_t oidx = (size_t)(ti * 64 + orow) * Ee + tj * 64 + ocol;
        if (y == 0) {
            u16 hh = f2bf(v); WqTh[oidx] = hh; WqTl[oidx] = f2bf(v - bf2f(hh));
        } else if (y == 1) {
            u16 hh = f2bf(v); WkTh[oidx] = hh; WkTl[oidx] = f2bf(v - bf2f(hh));
        } else if (y == 2) {
            WvT[oidx] = f2h(v);
        } else {
            WoT[oidx] = f2h(v);
        }
    }
}

// ---------------- GEMM body, 128(M) x 128(N) tile (m97 structure) ----------------
// SPLIT=1: bf16 hi/lo 3-MFMA. F16=1: fp16 MFMA.
// OUTMODE: 0 = f32 row-major, 1 = fp16 transposed [N][M], 2 = bf16 hi/lo row-major.
template <int SPLIT, int F16, int OUTMODE>
DI void gemm_body(const u16* __restrict__ Ah, const u16* __restrict__ Al,
                  const u16* __restrict__ Bh, const u16* __restrict__ Bl,
                  const float* __restrict__ bias,
                  u16* __restrict__ C16h, u16* __restrict__ C16l, float* __restrict__ Cf,
                  float scale, u16* As0, u16* As1, u16* Bs0, u16* Bs1) {
    constexpr int M = Mrows, N = Ee, K = Ee;
    const int tid = threadIdx.x;
    const int wave = tid >> 6, lane = tid & 63;
    const int quad = lane >> 4, l16 = lane & 15;
    const int m0 = blockIdx.y * 128, n0 = blockIdx.x * 128;
    const int wm = (wave >> 1) * 64, wn = (wave & 1) * 64;

    f32x4 acc[4][4];
#pragma unroll
    for (int i = 0; i < 4; i++)
#pragma unroll
        for (int j = 0; j < 4; j++) acc[i][j] = (f32x4)0.0f;

    for (int kk = 0; kk < K; kk += 32) {
        __syncthreads();
        // A tile 128x32 + B tile 128x32, 16B lane-linear chunks
#pragma unroll
        for (int i = 0; i < 2; i++) {
            int c = tid + i * 256;
            int row = c >> 2, j = c & 3;
            size_t ga = (size_t)(m0 + row) * K + kk + j * 8;
            gld16(Ah + ga, As0 + c * 8);
            if constexpr (SPLIT) gld16(Al + ga, As1 + c * 8);
            size_t gb = (size_t)(n0 + row) * K + kk + j * 8;
            gld16(Bh + gb, Bs0 + c * 8);
            if constexpr (SPLIT) gld16(Bl + gb, Bs1 + c * 8);
        }
        __syncthreads();

        s16x8 bf[4][2];
#pragma unroll
        for (int nt = 0; nt < 4; nt++) {
            int r = wn + nt * 16 + l16;
            bf[nt][0] = *(const s16x8*)&Bs0[r * 32 + quad * 8];
            if constexpr (SPLIT) bf[nt][1] = *(const s16x8*)&Bs1[r * 32 + quad * 8];
        }
#pragma unroll
        for (int mt = 0; mt < 4; mt++) {
            int r = wm + mt * 16 + l16;
            s16x8 a0 = *(const s16x8*)&As0[r * 32 + quad * 8];
            s16x8 a1;
            if constexpr (SPLIT) a1 = *(const s16x8*)&As1[r * 32 + quad * 8];
#pragma unroll
            for (int nt = 0; nt < 4; nt++) {
                if constexpr (F16) {
                    acc[mt][nt] = MFMA_F16(a0, bf[nt][0], acc[mt][nt]);
                } else {
                    acc[mt][nt] = MFMA_BF(a0, bf[nt][0], acc[mt][nt]);
                    if constexpr (SPLIT) {
                        acc[mt][nt] = MFMA_BF(a0, bf[nt][1], acc[mt][nt]);
                        acc[mt][nt] = MFMA_BF(a1, bf[nt][0], acc[mt][nt]);
                    }
                }
            }
        }
    }

    // epilogue — C/D layout: col = lane&15, row = quad*4 + reg
#pragma unroll
    for (int mt = 0; mt < 4; mt++)
#pragma unroll
        for (int nt = 0; nt < 4; nt++) {
            int gn = n0 + wn + nt * 16 + l16;
            float bs = bias[gn];
            if constexpr (OUTMODE == 1) {
                int gm = m0 + wm + mt * 16 + quad * 4;
                u16x4 pk;
#pragma unroll
                for (int r = 0; r < 4; r++) pk[r] = f2h((acc[mt][nt][r] + bs) * scale);
                *(u16x4*)&C16h[(size_t)gn * M + gm] = pk;
            } else {
#pragma unroll
                for (int r = 0; r < 4; r++) {
                    int gm = m0 + wm + mt * 16 + quad * 4 + r;
                    float v = (acc[mt][nt][r] + bs) * scale;
                    if constexpr (OUTMODE == 0) {
                        Cf[(size_t)gm * N + gn] = v;
                    } else {
                        u16 hh = f2bf(v);
                        C16h[(size_t)gm * N + gn] = hh;
                        C16l[(size_t)gm * N + gn] = f2bf(v - bf2f(hh));
                    }
                }
            }
        }
}

// ---------------- fused Q/K/V projections (grid.z selects) ----------------
__global__ __launch_bounds__(256, 3) void k_qkv(
    const u16* __restrict__ qh, const u16* __restrict__ ql,
    const u16* __restrict__ kh, const u16* __restrict__ kl,
    const u16* __restrict__ vh,
    const u16* __restrict__ WqTh, const u16* __restrict__ WqTl,
    const u16* __restrict__ WkTh, const u16* __restrict__ WkTl,
    const u16* __restrict__ WvT,
    const float* __restrict__ bq, const float* __restrict__ bk, const float* __restrict__ bv,
    u16* __restrict__ Qh, u16* __restrict__ Ql2,
    u16* __restrict__ Kh, u16* __restrict__ Kl2, u16* __restrict__ Vt) {
    __shared__ u16 As[2][128 * 32];
    __shared__ u16 Bs[2][128 * 32];
    int z = blockIdx.z;
    if (z == 0)
        gemm_body<1, 0, 2>(qh, ql, WqTh, WqTl, bq, Qh, Ql2, nullptr, QSCALE,
                           As[0], As[1], Bs[0], Bs[1]);
    else if (z == 1)
        gemm_body<1, 0, 2>(kh, kl, WkTh, WkTl, bk, Kh, Kl2, nullptr, 1.0f,
                           As[0], As[1], Bs[0], Bs[1]);
    else
        gemm_body<0, 1, 1>(vh, nullptr, WvT, nullptr, bv, Vt, nullptr, nullptr, 1.0f,
                           As[0], As[1], Bs[0], Bs[1]);
}

// ---------------- output projection: ctx(fp16) @ WoT(fp16) + bo -> f32 ----------------
__global__ __launch_bounds__(256, 3) void k_out(
    const u16* __restrict__ ctx, const u16* __restrict__ WoT,
    const float* __restrict__ bo, float* __restrict__ out) {
    __shared__ u16 As[128 * 32];
    __shared__ u16 Bs[128 * 32];
    gemm_body<0, 1, 0>(ctx, nullptr, WoT, nullptr, bo, nullptr, nullptr, out, 1.0f,
                       As, nullptr, Bs, nullptr);
}

// ---------------- flash attention: 32x32 MFMA, in-register softmax (T12) ------------
// r17: r16's T13 defer-max REGRESSED 84.3->86.9 (the wave-uniform branch mid-loop
// fences the compiler's softmax/pack/PV scheduling; VGPR 80->84, VALUBusy +2.5).
// Reverted to r15's branchless online softmax (measured 84.3us). Keeping: 32x32
// MFMA + in-register P via cvt_pkrtz+permlane32_swap (T12), gld_lds dbuf staging
// with inverse-swizzled source (rule #21), vectorized k_split3. Known residual:
// 6.3M bank-conflict cycles (~10us) — structural for b128 reads at row-stride
// 128B (32 rows into 8 chunk columns); not addressable without layout change.
__global__ __launch_bounds__(256, 2) void k_attn(
    const u16* __restrict__ Qh, const u16* __restrict__ Ql,
    const u16* __restrict__ Kh, const u16* __restrict__ Kl,
    const u16* __restrict__ Vt, u16* __restrict__ ctx) {
    const int bh = blockIdx.x;
    const int b = bh >> 4, h = bh & 15;
    const int q0 = blockIdx.y * 128;
    const int rowBase = b * Ss + q0;
    const int hc = h * 64;

    __shared__ u16 Ks[2][2][64 * 64];  // [buf][plane][row*64 + chunk] (32 KB)
    __shared__ u16 Vs[2][64 * 64];     // [buf][row*64 + chunk] fp16 (16 KB)

    const int tid = threadIdx.x;
    const int wave = tid >> 6, lane = tid & 63;
    const int l31 = lane & 31, hi = lane >> 5;
    const int swl = l31 & 7;

    // ---- staging: linear LDS dest, inverse-swizzled global source (rule #21)
    const int c0 = tid, c1 = tid + 256;
    const int srow0 = c0 >> 3, sj0 = (c0 & 7) ^ (srow0 & 7);
    const int srow1 = c1 >> 3, sj1 = (c1 & 7) ^ (srow1 & 7);

    auto stage = [&](int t0, int bf) {
        const size_t kb = (size_t)(b * Ss + t0) * Ee + hc;
        const size_t vb0 = (size_t)(hc + srow0) * Mrows + b * Ss + t0;
        const size_t vb1 = (size_t)(hc + srow1) * Mrows + b * Ss + t0;
        gld16(Kh + kb + (size_t)srow0 * Ee + sj0 * 8, &Ks[bf][0][c0 * 8]);
        gld16(Kh + kb + (size_t)srow1 * Ee + sj1 * 8, &Ks[bf][0][c1 * 8]);
        gld16(Kl + kb + (size_t)srow0 * Ee + sj0 * 8, &Ks[bf][1][c0 * 8]);
        gld16(Kl + kb + (size_t)srow1 * Ee + sj1 * 8, &Ks[bf][1][c1 * 8]);
        gld16(Vt + vb0 + sj0 * 8, &Vs[bf][c0 * 8]);
        gld16(Vt + vb1 + sj1 * 8, &Vs[bf][c1 * 8]);
    };

    // loop-invariant Q B-frags: col q = l31, k = d = ks*16 + hi*8 + e
    s16x8 bqh[4], bql[4];
    {
        const size_t qoff = (size_t)(rowBase + wave * 32 + l31) * Ee + hc + hi * 8;
#pragma unroll
        for (int ks = 0; ks < 4; ks++) {
            bqh[ks] = *(const s16x8*)(Qh + qoff + ks * 16);
            bql[ks] = *(const s16x8*)(Ql + qoff + ks * 16);
        }
    }

    f32x16 o[2];   // [dt]: O^T row d = (r&3)+8*(r>>2)+4*hi+32*dt, col q = l31
    o[0] = (f32x16)0.0f;
    o[1] = (f32x16)0.0f;
    float m_ = -1e30f, l_ = 0.f;

    stage(0, 0);
    __syncthreads();

    for (int t0 = 0; t0 < Ss; t0 += 64) {
        const int p = (t0 >> 6) & 1;
        if (t0 + 64 < Ss) stage(t0 + 64, p ^ 1);

        const u16* Kp = &Ks[p][0][0];
        const u16* Vp = &Vs[p][0];

        // S^T = K.Q^T (split): st[mt] row t = crow(r,hi)+32*mt, col q = l31
        f32x16 st[2];
        st[0] = (f32x16)0.0f;
        st[1] = (f32x16)0.0f;
        __builtin_amdgcn_s_setprio(1);
#pragma unroll
        for (int mt = 0; mt < 2; mt++) {
            const int rb = (mt * 32 + l31) * 64;
#pragma unroll
            for (int ks = 0; ks < 4; ks++) {
                const int sj = ((2 * ks + hi) ^ swl) * 8;
                s16x8 akh = *(const s16x8*)(Kp + rb + sj);
                s16x8 akl = *(const s16x8*)(Kp + rb + sj + 4096);
                st[mt] = MFMA32_BF(akh, bqh[ks], st[mt]);
                st[mt] = MFMA32_BF(akh, bql[ks], st[mt]);
                st[mt] = MFMA32_BF(akl, bqh[ks], st[mt]);
            }
        }
        __builtin_amdgcn_s_setprio(0);

        // online softmax: q = l31 (lane-local), partner rows live in lane^32
        float tmax = st[0][0];
#pragma unroll
        for (int mt = 0; mt < 2; mt++)
#pragma unroll
            for (int r = 0; r < 16; r++) tmax = fmaxf(tmax, st[mt][r]);
        tmax = fmaxf(tmax, __shfl_xor(tmax, 32));
        float mnew = fmaxf(m_, tmax);
        float al = ex2(m_ - mnew);
        m_ = mnew;
        float psum = 0.f;
#pragma unroll
        for (int mt = 0; mt < 2; mt++)
#pragma unroll
            for (int r = 0; r < 16; r++) {
                st[mt][r] = ex2(st[mt][r] - mnew);
                psum += st[mt][r];
            }
        psum += __shfl_xor(psum, 32);
        l_ = l_ * al + psum;
        o[0] *= al;
        o[1] *= al;

        // P -> PV B-frags in registers: 16 cvt_pkrtz + 8 permlane32_swap
        s16x8 pa[4];
#pragma unroll
        for (int kt = 0; kt < 4; kt++) {
            const int G0 = 2 * kt, G1 = 2 * kt + 1;
            const int m0_ = G0 >> 2, r0_ = (G0 & 3) * 4;
            const int m1_ = G1 >> 2, r1_ = (G1 & 3) * 4;
            u32 wA0 = pkrtz(st[m0_][r0_ + 0], st[m0_][r0_ + 1]);
            u32 wB0 = pkrtz(st[m0_][r0_ + 2], st[m0_][r0_ + 3]);
            u32 wA1 = pkrtz(st[m1_][r1_ + 0], st[m1_][r1_ + 1]);
            u32 wB1 = pkrtz(st[m1_][r1_ + 2], st[m1_][r1_ + 3]);
            u32x2 rA = __builtin_amdgcn_permlane32_swap(wA0, wA1, false, false);
            u32x2 rB = __builtin_amdgcn_permlane32_swap(wB0, wB1, false, false);
            u32x4 w;
            w[0] = rA[0]; w[1] = rB[0]; w[2] = rA[1]; w[3] = rB[1];
            pa[kt] = __builtin_bit_cast(s16x8, w);
        }

        // O^T += V^T . P^T : A = V^T (row d, k t), B = pa (col q, k t)
        __builtin_amdgcn_s_setprio(1);
#pragma unroll
        for (int dt = 0; dt < 2; dt++) {
            const int rbv = (dt * 32 + l31) * 64;
#pragma unroll
            for (int kt = 0; kt < 4; kt++) {
                const int sj = ((2 * kt + hi) ^ swl) * 8;
                s16x8 av = *(const s16x8*)(Vp + rbv + sj);
                o[dt] = MFMA32_F16(av, pa[kt], o[dt]);
            }
        }
        __builtin_amdgcn_s_setprio(0);

        __syncthreads();   // drains this iter's stage (vmcnt(0)) + flips buffer
    }

    // epilogue: ctx[q][hc+d] fp16, d = j + 8g + 4hi + 32dt -> 8B packed stores
    float inv = 1.0f / l_;
    const size_t obase = (size_t)(rowBase + wave * 32 + l31) * Ee + hc + hi * 4;
#pragma unroll
    for (int dt = 0; dt < 2; dt++)
#pragma unroll
        for (int g = 0; g < 4; g++) {
            u32x2 pk;
            pk[0] = pkrtz(o[dt][g * 4 + 0] * inv, o[dt][g * 4 + 1] * inv);
            pk[1] = pkrtz(o[dt][g * 4 + 2] * inv, o[dt][g * 4 + 3] * inv);
            *(u32x2*)&ctx[obase + dt * 32 + g * 8] = pk;
        }
}

extern "C" void kernel_launch(void* const* d_in, const int* in_sizes, int n_in,
                              void* d_out, int out_size, void* d_ws, size_t ws_size,
                              hipStream_t stream) {
    const float* q   = (const float*)d_in[0];
    const float* kin = (const float*)d_in[1];
    const float* v   = (const float*)d_in[2];
    const float* Wq  = (const float*)d_in[3];
    const float* Wk  = (const float*)d_in[4];
    const float* Wv  = (const float*)d_in[5];
    const float* bq  = (const float*)d_in[6];
    const float* bk  = (const float*)d_in[7];
    const float* bv  = (const float*)d_in[8];
    const float* Wo  = (const float*)d_in[9];
    const float* bo  = (const float*)d_in[10];

    u16* ws = (u16*)d_ws;
    u16 *qh = ws,          *ql = ws + NE,     *kh = ws + 2 * NE, *kl = ws + 3 * NE;
    u16 *vh = ws + 4 * NE;
    u16 *Qh = ws + 5 * NE, *Ql = ws + 6 * NE, *Kh = ws + 7 * NE, *Kl = ws + 8 * NE;
    u16 *Vt = ws + 9 * NE, *ctx = ws + 10 * NE;
    u16 *WqTh = ws + 11 * NE;
    u16 *WqTl = WqTh + WN, *WkTh = WqTh + 2 * WN, *WkTl = WqTh + 3 * WN;
    u16 *WvT = WqTh + 4 * WN, *WoT = WqTh + 5 * WN;

    dim3 b256(256);
    k_split3<<<dim3(NE / 2048, 3), b256, 0, stream>>>(q, kin, v, qh, ql, kh, kl, vh);
    k_wprep<<<dim3(256, 4), b256, 0, stream>>>(Wq, Wk, Wv, Wo,
                                               WqTh, WqTl, WkTh, WkTl, WvT, WoT);

    k_qkv<<<dim3(8, 32, 3), b256, 0, stream>>>(qh, ql, kh, kl, vh,
                                               WqTh, WqTl, WkTh, WkTl, WvT,
                                               bq, bk, bv, Qh, Ql, Kh, Kl, Vt);

    k_attn<<<dim3(Bb * Hh, Ss / 128), b256, 0, stream>>>(Qh, Ql, Kh, Kl, Vt, ctx);

    k_out<<<dim3(8, 32), b256, 0, stream>>>(ctx, WoT, bo, (float*)d_out);
}